// Round 1
// baseline (1232.641 us; speedup 1.0000x reference)
//
#include <hip/hip_runtime.h>

#define DIM 64
#define HID 128
#define NROWS 16
#define NT 256

__device__ __forceinline__ float sigm(float x) { return 1.f / (1.f + __expf(-x)); }
__device__ __forceinline__ float siluf(float x) { return x * sigm(x); }
__device__ __forceinline__ float silup(float x) { float s = sigm(x); return s + x * s * (1.f - s); }
__device__ __forceinline__ float softplusf(float x) {
    if (x > 20.f) return x;
    return log1pf(__expf(x));
}

// scalar net fwd+bwd: buf1=a1, buf2=h1->da1, buf3=a2, buf4=h2->da2
#define SCALAR_NET(W1, B1, W2, B2, W3, B3, GOUT, STOREH)                              \
    do {                                                                              \
        for (int id = tid; id < NROWS * HID; id += NT) {                              \
            int r = id >> 7, h = id & (HID - 1);                                      \
            float acc = B1[h];                                                        \
            _Pragma("unroll")                                                         \
            for (int c = 0; c < DIM; ++c) acc += zs[r][c] * W1[c * HID + h];          \
            buf1[r][h] = acc; buf2[r][h] = siluf(acc);                                \
        }                                                                             \
        __syncthreads();                                                              \
        for (int id = tid; id < NROWS * HID; id += NT) {                              \
            int r = id >> 7, h = id & (HID - 1);                                      \
            float acc = B2[h];                                                        \
            _Pragma("unroll 8")                                                       \
            for (int c = 0; c < HID; ++c) acc += buf2[r][c] * W2[c * HID + h];        \
            buf3[r][h] = acc; buf4[r][h] = siluf(acc);                                \
        }                                                                             \
        __syncthreads();                                                              \
        if (tid < NROWS) {                                                            \
            float acc = B3[0];                                                        \
            for (int c = 0; c < HID; ++c) acc += buf4[tid][c] * W3[c];                \
            if (STOREH) Hrow[tid] = softplusf(acc);                                   \
            srow[tid] = sigm(acc);                                                    \
        }                                                                             \
        __syncthreads();                                                              \
        for (int id = tid; id < NROWS * HID; id += NT) {                              \
            int r = id >> 7, h = id & (HID - 1);                                      \
            buf4[r][h] = srow[r] * W3[h] * silup(buf3[r][h]);                         \
        }                                                                             \
        __syncthreads();                                                              \
        for (int id = tid; id < NROWS * HID; id += NT) {                              \
            int r = id >> 7, i = id & (HID - 1);                                      \
            float acc = 0.f;                                                          \
            _Pragma("unroll 8")                                                       \
            for (int c = 0; c < HID; ++c) acc += W2[i * HID + c] * buf4[r][c];        \
            buf2[r][i] = acc * silup(buf1[r][i]);                                     \
        }                                                                             \
        __syncthreads();                                                              \
        for (int id = tid; id < NROWS * DIM; id += NT) {                              \
            int r = id >> 6, k = id & (DIM - 1);                                      \
            float acc = 0.f;                                                          \
            _Pragma("unroll 8")                                                       \
            for (int c = 0; c < HID; ++c) acc += W1[k * HID + c] * buf2[r][c];        \
            GOUT[r][k] = acc;                                                         \
        }                                                                             \
        __syncthreads();                                                              \
    } while (0)

extern "C" __global__ __launch_bounds__(NT, 2)
void ph_kernel(const float* __restrict__ z,
               const float* __restrict__ Hw1, const float* __restrict__ Hb1,
               const float* __restrict__ Hw2, const float* __restrict__ Hb2,
               const float* __restrict__ Hw3, const float* __restrict__ Hb3,
               const float* __restrict__ Dw1, const float* __restrict__ Db1,
               const float* __restrict__ Dw2, const float* __restrict__ Db2,
               const float* __restrict__ Dw3, const float* __restrict__ Db3,
               const float* __restrict__ Jw1, const float* __restrict__ Jb1,
               const float* __restrict__ Jw2, const float* __restrict__ Jb2,
               const float* __restrict__ Bw1, const float* __restrict__ Bb1,
               const float* __restrict__ Bw2, const float* __restrict__ Bb2,
               const float* __restrict__ uw1, const float* __restrict__ ub1,
               const float* __restrict__ uw2, const float* __restrict__ ub2,
               const float* __restrict__ dtl, const float* __restrict__ etg,
               float* __restrict__ out)
{
    __shared__ __align__(16) float zs[NROWS][DIM];
    __shared__ __align__(16) float buf1[NROWS][HID];
    __shared__ __align__(16) float buf2[NROWS][HID];
    __shared__ __align__(16) float buf3[NROWS][HID];
    __shared__ __align__(16) float buf4[NROWS][HID];
    __shared__ __align__(16) float gH[NROWS][DIM];
    __shared__ __align__(16) float gD[NROWS][DIM];
    __shared__ __align__(16) float uv[NROWS][DIM];
    __shared__ __align__(16) float consA[NROWS][DIM];
    __shared__ __align__(16) float dissA[NROWS][DIM];
    __shared__ __align__(16) float vA[NROWS][DIM];
    __shared__ float Hrow[NROWS];
    __shared__ float srow[NROWS];

    const int tid = threadIdx.x;
    const int r0 = blockIdx.x * NROWS;

    // stage z tile (16 rows x 64) via float4
    {
        const float4* zg = reinterpret_cast<const float4*>(z) + (size_t)r0 * (DIM / 4);
        reinterpret_cast<float4*>(&zs[0][0])[tid] = zg[tid];
    }
    for (int k2 = tid; k2 < NROWS * DIM; k2 += NT) {
        (&consA[0][0])[k2] = 0.f;
        (&vA[0][0])[k2] = 0.f;
    }
    __syncthreads();

    SCALAR_NET(Hw1, Hb1, Hw2, Hb2, Hw3, Hb3, gH, 1);
    SCALAR_NET(Dw1, Db1, Dw2, Db2, Dw3, Db3, gD, 0);

    // u-net layer1 (tanh) -> buf3
    for (int id = tid; id < NROWS * HID; id += NT) {
        int r = id >> 7, h = id & (HID - 1);
        float acc = ub1[h];
        #pragma unroll
        for (int c = 0; c < DIM; ++c) acc += zs[r][c] * uw1[c * HID + h];
        buf3[r][h] = tanhf(acc);
    }
    // hJ -> buf1, hB -> buf2 (buffers free after D net)
    for (int id = tid; id < NROWS * HID; id += NT) {
        int r = id >> 7, h = id & (HID - 1);
        float aJ = Jb1[h], aB = Bb1[h];
        #pragma unroll
        for (int c = 0; c < DIM; ++c) {
            float zv = zs[r][c];
            aJ += zv * Jw1[c * HID + h];
            aB += zv * Bw1[c * HID + h];
        }
        buf1[r][h] = siluf(aJ);
        buf2[r][h] = siluf(aB);
    }
    __syncthreads();
    // u-net layer2 -> uv
    for (int id = tid; id < NROWS * DIM; id += NT) {
        int r = id >> 6, k = id & (DIM - 1);
        float acc = ub2[k];
        #pragma unroll 8
        for (int c = 0; c < HID; ++c) acc += buf3[r][c] * uw2[c * DIM + k];
        uv[r][k] = acc;
    }
    __syncthreads();

    const int jg = tid & 15;   // 16 column groups of 4
    const int igl = tid >> 4;  // 0..15 ; within a wave: 4 distinct values
    const int j0 = jg * 4;

    // ---------- Phase 2A: cons = (A - A^T) gH ----------
    {
        float consm[NROWS][4];
        #pragma unroll
        for (int r = 0; r < NROWS; ++r) {
            #pragma unroll
            for (int cc = 0; cc < 4; ++cc) consm[r][cc] = 0.f;
        }
        #pragma unroll 1
        for (int s = 0; s < 4; ++s) {
            const int i = igl + 16 * s;  // unique i per wave
            const float4 bias4 = *reinterpret_cast<const float4*>(Jb2 + i * DIM + j0);
            float a[NROWS][4];
            #pragma unroll
            for (int r = 0; r < NROWS; ++r) {
                a[r][0] = bias4.x; a[r][1] = bias4.y; a[r][2] = bias4.z; a[r][3] = bias4.w;
            }
            const float* wp = Jw2 + i * DIM + j0;
            #pragma unroll 2
            for (int h = 0; h < HID; ++h) {
                const float4 w4 = *reinterpret_cast<const float4*>(wp + (size_t)h * (DIM * DIM));
                #pragma unroll
                for (int r = 0; r < NROWS; ++r) {
                    const float hv = buf1[r][h];
                    a[r][0] += hv * w4.x; a[r][1] += hv * w4.y;
                    a[r][2] += hv * w4.z; a[r][3] += hv * w4.w;
                }
            }
            #pragma unroll
            for (int r = 0; r < NROWS; ++r) {
                const float4 gh4 = *reinterpret_cast<const float4*>(&gH[r][j0]);
                float p = a[r][0] * gh4.x + a[r][1] * gh4.y + a[r][2] * gh4.z + a[r][3] * gh4.w;
                p += __shfl_xor(p, 1); p += __shfl_xor(p, 2);
                p += __shfl_xor(p, 4); p += __shfl_xor(p, 8);
                if (jg == 0) atomicAdd(&consA[r][i], p);
                const float ghi = gH[r][i];
                consm[r][0] += a[r][0] * ghi; consm[r][1] += a[r][1] * ghi;
                consm[r][2] += a[r][2] * ghi; consm[r][3] += a[r][3] * ghi;
            }
        }
        #pragma unroll
        for (int r = 0; r < NROWS; ++r) {
            #pragma unroll
            for (int cc = 0; cc < 4; ++cc)
                atomicAdd(&consA[r][j0 + cc], -consm[r][cc]);
        }
    }

    // ---------- Phase 2B: v = Bm^T gD ----------
    {
        float vp[NROWS][4];
        #pragma unroll
        for (int r = 0; r < NROWS; ++r) {
            #pragma unroll
            for (int cc = 0; cc < 4; ++cc) vp[r][cc] = 0.f;
        }
        #pragma unroll 1
        for (int s = 0; s < 4; ++s) {
            const int j = igl + 16 * s;
            const float4 bias4 = *reinterpret_cast<const float4*>(Bb2 + j * DIM + j0);
            float a[NROWS][4];
            #pragma unroll
            for (int r = 0; r < NROWS; ++r) {
                a[r][0] = bias4.x; a[r][1] = bias4.y; a[r][2] = bias4.z; a[r][3] = bias4.w;
            }
            const float* wp = Bw2 + j * DIM + j0;
            #pragma unroll 2
            for (int h = 0; h < HID; ++h) {
                const float4 w4 = *reinterpret_cast<const float4*>(wp + (size_t)h * (DIM * DIM));
                #pragma unroll
                for (int r = 0; r < NROWS; ++r) {
                    const float hv = buf2[r][h];
                    a[r][0] += hv * w4.x; a[r][1] += hv * w4.y;
                    a[r][2] += hv * w4.z; a[r][3] += hv * w4.w;
                }
            }
            #pragma unroll
            for (int r = 0; r < NROWS; ++r) {
                const float gdj = gD[r][j];
                vp[r][0] += a[r][0] * gdj; vp[r][1] += a[r][1] * gdj;
                vp[r][2] += a[r][2] * gdj; vp[r][3] += a[r][3] * gdj;
            }
        }
        #pragma unroll
        for (int r = 0; r < NROWS; ++r) {
            #pragma unroll
            for (int cc = 0; cc < 4; ++cc)
                atomicAdd(&vA[r][j0 + cc], vp[r][cc]);
        }
    }
    __syncthreads();

    // ---------- Phase 2C: diss_pos = Bm v  (diss = -diss_pos) ----------
    {
        #pragma unroll 1
        for (int s = 0; s < 4; ++s) {
            const int i = igl + 16 * s;  // unique i per wave
            const float4 bias4 = *reinterpret_cast<const float4*>(Bb2 + i * DIM + j0);
            float a[NROWS][4];
            #pragma unroll
            for (int r = 0; r < NROWS; ++r) {
                a[r][0] = bias4.x; a[r][1] = bias4.y; a[r][2] = bias4.z; a[r][3] = bias4.w;
            }
            const float* wp = Bw2 + i * DIM + j0;
            #pragma unroll 2
            for (int h = 0; h < HID; ++h) {
                const float4 w4 = *reinterpret_cast<const float4*>(wp + (size_t)h * (DIM * DIM));
                #pragma unroll
                for (int r = 0; r < NROWS; ++r) {
                    const float hv = buf2[r][h];
                    a[r][0] += hv * w4.x; a[r][1] += hv * w4.y;
                    a[r][2] += hv * w4.z; a[r][3] += hv * w4.w;
                }
            }
            #pragma unroll
            for (int r = 0; r < NROWS; ++r) {
                const float4 v4 = *reinterpret_cast<const float4*>(&vA[r][j0]);
                float p = a[r][0] * v4.x + a[r][1] * v4.y + a[r][2] * v4.z + a[r][3] * v4.w;
                p += __shfl_xor(p, 1); p += __shfl_xor(p, 2);
                p += __shfl_xor(p, 4); p += __shfl_xor(p, 8);
                if (jg == 0) dissA[r][i] = p;
            }
        }
    }
    __syncthreads();

    // ---------- Phase 3: out = z + dt * (cons - R gD + 0.1*(Et - H)*u) ----------
    const float dt = 0.1f * sigm(dtl[0]);
    const float et = etg[0];
    for (int id = tid; id < NROWS * DIM; id += NT) {
        int r = id >> 6, c = id & (DIM - 1);
        float dz = consA[r][c] - dissA[r][c] + 0.1f * (et - Hrow[r]) * uv[r][c];
        out[(size_t)(r0 + r) * DIM + c] = zs[r][c] + dt * dz;
    }
}

extern "C" void kernel_launch(void* const* d_in, const int* in_sizes, int n_in,
                              void* d_out, int out_size, void* d_ws, size_t ws_size,
                              hipStream_t stream) {
    const float* p[27];
    for (int i = 0; i < 27; ++i) p[i] = (const float*)d_in[i];
    const int batch = in_sizes[0] / DIM;
    dim3 grid(batch / NROWS), block(NT);
    hipLaunchKernelGGL(ph_kernel, grid, block, 0, stream,
                       p[0],
                       p[1], p[2], p[3], p[4], p[5], p[6],
                       p[7], p[8], p[9], p[10], p[11], p[12],
                       p[13], p[14], p[15], p[16],
                       p[17], p[18], p[19], p[20],
                       p[21], p[22], p[23], p[24],
                       p[25], p[26],
                       (float*)d_out);
}

// Round 2
// 843.476 us; speedup vs baseline: 1.4614x; 1.4614x over previous
//
#include <hip/hip_runtime.h>

#define DIM 64
#define HID 128
#define NROWS 16
#define NT 256

typedef __attribute__((ext_vector_type(8))) short short8;
typedef __attribute__((ext_vector_type(4))) float f32x4;

__device__ __forceinline__ float sigm(float x) { return 1.f / (1.f + __expf(-x)); }
__device__ __forceinline__ float siluf(float x) { return x * sigm(x); }
__device__ __forceinline__ float silup(float x) { float s = sigm(x); return s + x * s * (1.f - s); }
__device__ __forceinline__ float softplusf(float x) {
    if (x > 20.f) return x;
    return log1pf(__expf(x));
}
__device__ __forceinline__ unsigned short f2bf(float f) {
    union { float f; unsigned int u; } v; v.f = f;
    unsigned int r = v.u + 0x7fffu + ((v.u >> 16) & 1u);
    return (unsigned short)(r >> 16);
}

// ---------------- prep: transpose+convert Jw2/Bw2 [128][4096] f32 -> [4096][128] bf16 ----------------
extern "C" __global__ __launch_bounds__(256)
void prep_kernel(const float* __restrict__ Jw2, const float* __restrict__ Bw2,
                 unsigned short* __restrict__ JT, unsigned short* __restrict__ BT)
{
    __shared__ unsigned short t[16][136];
    const int b = blockIdx.x;                  // 0..511
    const float* src = (b & 256) ? Bw2 : Jw2;
    unsigned short* dst = (b & 256) ? BT : JT;
    const int col0 = (b & 255) * 16;
    const int tid = threadIdx.x;
    #pragma unroll
    for (int it = 0; it < 8; ++it) {
        int idx = it * 256 + tid;
        int h = idx >> 4, c = idx & 15;
        t[c][h] = f2bf(src[h * 4096 + col0 + c]);
    }
    __syncthreads();
    #pragma unroll
    for (int it = 0; it < 8; ++it) {
        int idx = it * 256 + tid;
        int c = idx >> 7, h = idx & 127;
        dst[(size_t)(col0 + c) * 128 + h] = t[c][h];
    }
}

// scalar net fwd+bwd with 3 LDS buffers: buf1=a1, buf2=h1->da1, buf3=a2->da2
#define SCALAR_NET(W1, B1, W2, B2, W3, B3, GOUT, STOREH)                              \
    do {                                                                              \
        for (int id = tid; id < NROWS * HID; id += NT) {                              \
            int r = id >> 7, h = id & (HID - 1);                                      \
            float acc = B1[h];                                                        \
            _Pragma("unroll")                                                         \
            for (int c = 0; c < DIM; ++c) acc += zs[r][c] * W1[c * HID + h];          \
            buf1[r][h] = acc; buf2[r][h] = siluf(acc);                                \
        }                                                                             \
        __syncthreads();                                                              \
        for (int id = tid; id < NROWS * HID; id += NT) {                              \
            int r = id >> 7, h = id & (HID - 1);                                      \
            float acc = B2[h];                                                        \
            _Pragma("unroll 8")                                                       \
            for (int c = 0; c < HID; ++c) acc += buf2[r][c] * W2[c * HID + h];        \
            buf3[r][h] = acc;                                                         \
        }                                                                             \
        __syncthreads();                                                              \
        {                                                                             \
            int r = tid >> 4, pp = tid & 15;                                          \
            float acc = 0.f;                                                          \
            _Pragma("unroll")                                                         \
            for (int c8 = 0; c8 < 8; ++c8) {                                          \
                int c = pp * 8 + c8;                                                  \
                acc += siluf(buf3[r][c]) * W3[c];                                     \
            }                                                                         \
            acc += __shfl_xor(acc, 1); acc += __shfl_xor(acc, 2);                     \
            acc += __shfl_xor(acc, 4); acc += __shfl_xor(acc, 8);                     \
            if (pp == 0) {                                                            \
                float a3 = acc + B3[0];                                               \
                if (STOREH) Hrow[r] = softplusf(a3);                                  \
                srow[r] = sigm(a3);                                                   \
            }                                                                         \
        }                                                                             \
        __syncthreads();                                                              \
        for (int id = tid; id < NROWS * HID; id += NT) {                              \
            int r = id >> 7, h = id & (HID - 1);                                      \
            buf3[r][h] = srow[r] * W3[h] * silup(buf3[r][h]);                         \
        }                                                                             \
        __syncthreads();                                                              \
        for (int id = tid; id < NROWS * HID; id += NT) {                              \
            int r = id >> 7, i = id & (HID - 1);                                      \
            float acc = 0.f;                                                          \
            _Pragma("unroll 8")                                                       \
            for (int c = 0; c < HID; ++c) acc += W2[i * HID + c] * buf3[r][c];        \
            buf2[r][i] = acc * silup(buf1[r][i]);                                     \
        }                                                                             \
        __syncthreads();                                                              \
        for (int id = tid; id < NROWS * DIM; id += NT) {                              \
            int r = id >> 6, k = id & (DIM - 1);                                      \
            float acc = 0.f;                                                          \
            _Pragma("unroll 8")                                                       \
            for (int c = 0; c < HID; ++c) acc += W1[k * HID + c] * buf2[r][c];        \
            GOUT[r][k] = acc;                                                         \
        }                                                                             \
        __syncthreads();                                                              \
    } while (0)

extern "C" __global__ __launch_bounds__(NT, 2)
void ph_kernel(const float* __restrict__ z,
               const float* __restrict__ Hw1, const float* __restrict__ Hb1,
               const float* __restrict__ Hw2, const float* __restrict__ Hb2,
               const float* __restrict__ Hw3, const float* __restrict__ Hb3,
               const float* __restrict__ Dw1, const float* __restrict__ Db1,
               const float* __restrict__ Dw2, const float* __restrict__ Db2,
               const float* __restrict__ Dw3, const float* __restrict__ Db3,
               const float* __restrict__ Jw1, const float* __restrict__ Jb1,
               const float* __restrict__ Jb2,
               const float* __restrict__ Bw1, const float* __restrict__ Bb1,
               const float* __restrict__ Bb2,
               const float* __restrict__ uw1, const float* __restrict__ ub1,
               const float* __restrict__ uw2, const float* __restrict__ ub2,
               const float* __restrict__ dtl, const float* __restrict__ etg,
               const unsigned short* __restrict__ JT, const unsigned short* __restrict__ BT,
               float* __restrict__ out)
{
    __shared__ __align__(16) float zs[NROWS][DIM];
    __shared__ __align__(16) float buf1[NROWS][HID];
    __shared__ __align__(16) float buf2[NROWS][HID];
    __shared__ __align__(16) float buf3[NROWS][HID];
    __shared__ __align__(16) float gHs[NROWS][68];
    __shared__ __align__(16) float gDs[NROWS][68];
    __shared__ __align__(16) float uvs[NROWS][DIM];
    __shared__ __align__(16) unsigned short hJs[NROWS][136];
    __shared__ __align__(16) unsigned short hBs[NROWS][136];
    __shared__ __align__(16) float consL[NROWS][68];
    __shared__ __align__(16) float dissL[NROWS][68];
    __shared__ __align__(16) float vsL[NROWS][68];
    __shared__ float Hrow[NROWS];
    __shared__ float srow[NROWS];

    const int tid = threadIdx.x;
    const int r0 = blockIdx.x * NROWS;

    // stage z tile
    {
        const float4* zg = reinterpret_cast<const float4*>(z) + (size_t)r0 * (DIM / 4);
        reinterpret_cast<float4*>(&zs[0][0])[tid] = zg[tid];
    }
    for (int k2 = tid; k2 < NROWS * 68; k2 += NT) {
        (&consL[0][0])[k2] = 0.f;
        (&dissL[0][0])[k2] = 0.f;
    }
    __syncthreads();

    SCALAR_NET(Hw1, Hb1, Hw2, Hb2, Hw3, Hb3, gHs, 1);
    SCALAR_NET(Dw1, Db1, Dw2, Db2, Dw3, Db3, gDs, 0);

    // J/B/u layer 1 fused (share z reads); u tanh -> buf3
    for (int id = tid; id < NROWS * HID; id += NT) {
        int r = id >> 7, h = id & (HID - 1);
        float aJ = Jb1[h], aB = Bb1[h], aU = ub1[h];
        #pragma unroll
        for (int c = 0; c < DIM; ++c) {
            float zv = zs[r][c];
            aJ += zv * Jw1[c * HID + h];
            aB += zv * Bw1[c * HID + h];
            aU += zv * uw1[c * HID + h];
        }
        hJs[r][h] = f2bf(siluf(aJ));
        hBs[r][h] = f2bf(siluf(aB));
        buf3[r][h] = tanhf(aU);
    }
    __syncthreads();
    // u layer 2 -> uvs
    for (int id = tid; id < NROWS * DIM; id += NT) {
        int r = id >> 6, k = id & (DIM - 1);
        float acc = ub2[k];
        #pragma unroll 8
        for (int c = 0; c < HID; ++c) acc += buf3[r][c] * uw2[c * DIM + k];
        uvs[r][k] = acc;
    }
    __syncthreads();

    // ---------------- heavy passes via MFMA ----------------
    const int lane = tid & 63;
    const int wv = tid >> 6;       // wave 0..3 -> col tile
    const int co = wv << 4;        // col offset within 64-chunk
    const int cl = lane & 15;
    const int qq = lane >> 4;      // quarter
    const int rbase = qq << 2;     // acc reg q -> row rbase+q

    // ---- J pass: cons = (A - A^T) gH ----
    {
        short8 ja0 = *(const short8*)&hJs[cl][(qq << 3)];
        short8 ja1 = *(const short8*)&hJs[cl][32 + (qq << 3)];
        short8 ja2 = *(const short8*)&hJs[cl][64 + (qq << 3)];
        short8 ja3 = *(const short8*)&hJs[cl][96 + (qq << 3)];
        float cm[4] = {0.f, 0.f, 0.f, 0.f};
        #pragma unroll 2
        for (int i = 0; i < DIM; ++i) {
            const unsigned short* wp = JT + (((size_t)(i << 6) + co + cl) << 7) + (qq << 3);
            short8 b0 = *(const short8*)(wp);
            short8 b1 = *(const short8*)(wp + 32);
            short8 b2 = *(const short8*)(wp + 64);
            short8 b3 = *(const short8*)(wp + 96);
            float bias = Jb2[(i << 6) + co + cl];
            f32x4 acc = {0.f, 0.f, 0.f, 0.f};
            acc = __builtin_amdgcn_mfma_f32_16x16x32_bf16(ja0, b0, acc, 0, 0, 0);
            acc = __builtin_amdgcn_mfma_f32_16x16x32_bf16(ja1, b1, acc, 0, 0, 0);
            acc = __builtin_amdgcn_mfma_f32_16x16x32_bf16(ja2, b2, acc, 0, 0, 0);
            acc = __builtin_amdgcn_mfma_f32_16x16x32_bf16(ja3, b3, acc, 0, 0, 0);
            float psum[4];
            #pragma unroll
            for (int q = 0; q < 4; ++q) {
                int r = rbase + q;
                float y = acc[q] + bias;
                cm[q] += y * gHs[r][i];
                psum[q] = y * gHs[r][co + cl];
            }
            #pragma unroll
            for (int q = 0; q < 4; ++q) {
                float p = psum[q];
                p += __shfl_xor(p, 1); p += __shfl_xor(p, 2);
                p += __shfl_xor(p, 4); p += __shfl_xor(p, 8);
                if (cl == 0) atomicAdd(&consL[rbase + q][i], p);
            }
        }
        #pragma unroll
        for (int q = 0; q < 4; ++q)
            atomicAdd(&consL[rbase + q][co + cl], -cm[q]);
    }

    // ---- B pass 1: v = Bm^T gD ----
    {
        short8 ba0 = *(const short8*)&hBs[cl][(qq << 3)];
        short8 ba1 = *(const short8*)&hBs[cl][32 + (qq << 3)];
        short8 ba2 = *(const short8*)&hBs[cl][64 + (qq << 3)];
        short8 ba3 = *(const short8*)&hBs[cl][96 + (qq << 3)];
        float vr[4] = {0.f, 0.f, 0.f, 0.f};
        #pragma unroll 2
        for (int i = 0; i < DIM; ++i) {
            const unsigned short* wp = BT + (((size_t)(i << 6) + co + cl) << 7) + (qq << 3);
            short8 b0 = *(const short8*)(wp);
            short8 b1 = *(const short8*)(wp + 32);
            short8 b2 = *(const short8*)(wp + 64);
            short8 b3 = *(const short8*)(wp + 96);
            float bias = Bb2[(i << 6) + co + cl];
            f32x4 acc = {0.f, 0.f, 0.f, 0.f};
            acc = __builtin_amdgcn_mfma_f32_16x16x32_bf16(ba0, b0, acc, 0, 0, 0);
            acc = __builtin_amdgcn_mfma_f32_16x16x32_bf16(ba1, b1, acc, 0, 0, 0);
            acc = __builtin_amdgcn_mfma_f32_16x16x32_bf16(ba2, b2, acc, 0, 0, 0);
            acc = __builtin_amdgcn_mfma_f32_16x16x32_bf16(ba3, b3, acc, 0, 0, 0);
            #pragma unroll
            for (int q = 0; q < 4; ++q)
                vr[q] += (acc[q] + bias) * gDs[rbase + q][i];
        }
        #pragma unroll
        for (int q = 0; q < 4; ++q)
            vsL[rbase + q][co + cl] = vr[q];
    }
    __syncthreads();

    // ---- B pass 2: dissL = Bm v ----
    {
        short8 ba0 = *(const short8*)&hBs[cl][(qq << 3)];
        short8 ba1 = *(const short8*)&hBs[cl][32 + (qq << 3)];
        short8 ba2 = *(const short8*)&hBs[cl][64 + (qq << 3)];
        short8 ba3 = *(const short8*)&hBs[cl][96 + (qq << 3)];
        #pragma unroll 2
        for (int i = 0; i < DIM; ++i) {
            const unsigned short* wp = BT + (((size_t)(i << 6) + co + cl) << 7) + (qq << 3);
            short8 b0 = *(const short8*)(wp);
            short8 b1 = *(const short8*)(wp + 32);
            short8 b2 = *(const short8*)(wp + 64);
            short8 b3 = *(const short8*)(wp + 96);
            float bias = Bb2[(i << 6) + co + cl];
            f32x4 acc = {0.f, 0.f, 0.f, 0.f};
            acc = __builtin_amdgcn_mfma_f32_16x16x32_bf16(ba0, b0, acc, 0, 0, 0);
            acc = __builtin_amdgcn_mfma_f32_16x16x32_bf16(ba1, b1, acc, 0, 0, 0);
            acc = __builtin_amdgcn_mfma_f32_16x16x32_bf16(ba2, b2, acc, 0, 0, 0);
            acc = __builtin_amdgcn_mfma_f32_16x16x32_bf16(ba3, b3, acc, 0, 0, 0);
            float psum[4];
            #pragma unroll
            for (int q = 0; q < 4; ++q)
                psum[q] = (acc[q] + bias) * vsL[rbase + q][co + cl];
            #pragma unroll
            for (int q = 0; q < 4; ++q) {
                float p = psum[q];
                p += __shfl_xor(p, 1); p += __shfl_xor(p, 2);
                p += __shfl_xor(p, 4); p += __shfl_xor(p, 8);
                if (cl == 0) atomicAdd(&dissL[rbase + q][i], p);
            }
        }
    }
    __syncthreads();

    // ---------------- epilogue ----------------
    const float dt = 0.1f * sigm(dtl[0]);
    const float et = etg[0];
    for (int id = tid; id < NROWS * DIM; id += NT) {
        int r = id >> 6, c = id & (DIM - 1);
        float dz = consL[r][c] - dissL[r][c] + 0.1f * (et - Hrow[r]) * uvs[r][c];
        out[(size_t)(r0 + r) * DIM + c] = zs[r][c] + dt * dz;
    }
}

extern "C" void kernel_launch(void* const* d_in, const int* in_sizes, int n_in,
                              void* d_out, int out_size, void* d_ws, size_t ws_size,
                              hipStream_t stream) {
    const float* p[27];
    for (int i = 0; i < 27; ++i) p[i] = (const float*)d_in[i];
    unsigned short* JT = (unsigned short*)d_ws;
    unsigned short* BT = JT + (size_t)4096 * 128;

    hipLaunchKernelGGL(prep_kernel, dim3(512), dim3(256), 0, stream,
                       p[15], p[19], JT, BT);

    const int batch = in_sizes[0] / DIM;
    dim3 grid(batch / NROWS), block(NT);
    hipLaunchKernelGGL(ph_kernel, grid, block, 0, stream,
                       p[0],
                       p[1], p[2], p[3], p[4], p[5], p[6],
                       p[7], p[8], p[9], p[10], p[11], p[12],
                       p[13], p[14], p[16],
                       p[17], p[18], p[20],
                       p[21], p[22], p[23], p[24],
                       p[25], p[26],
                       JT, BT,
                       (float*)d_out);
}

// Round 3
// 606.613 us; speedup vs baseline: 2.0320x; 1.3905x over previous
//
#include <hip/hip_runtime.h>

#define DIM 64
#define HID 128
#define NROWS 16
#define NT 256

typedef __attribute__((ext_vector_type(8))) short short8;
typedef __attribute__((ext_vector_type(4))) float f32x4;
typedef unsigned short ushort_t;

__device__ __forceinline__ float sigm(float x) { return 1.f / (1.f + __expf(-x)); }
__device__ __forceinline__ float siluf(float x) { return x * sigm(x); }
__device__ __forceinline__ float silup(float x) { float s = sigm(x); return s + x * s * (1.f - s); }
__device__ __forceinline__ float softplusf(float x) {
    if (x > 20.f) return x;
    return log1pf(__expf(x));
}
__device__ __forceinline__ ushort_t f2bf(float f) {
    union { float f; unsigned int u; } v; v.f = f;
    unsigned int r = v.u + 0x7fffu + ((v.u >> 16) & 1u);
    return (ushort_t)(r >> 16);
}
__device__ __forceinline__ float bf2f(ushort_t u) {
    union { unsigned int u; float f; } v; v.u = ((unsigned int)u) << 16;
    return v.f;
}
__device__ __forceinline__ unsigned int cvtpk(float lo, float hi) {
    unsigned int r;
    asm("v_cvt_pk_bf16_f32 %0, %1, %2" : "=v"(r) : "v"(lo), "v"(hi));
    return r;
}

// ================= prep: build frag-layout weight matrices in ws =================
// Layout: W'[(kt*64 + n)*32 + ks], k = kt*32+ks. For JW/BW2: k=(j,h) => j=k>>7,h=k&127, n=i.
// For BW1: k=(i,h), n=j.
extern "C" __global__ __launch_bounds__(256)
void prep2_kernel(const float* __restrict__ Jw2, const float* __restrict__ Jb2,
                  const float* __restrict__ Bw2, const float* __restrict__ Bb2,
                  ushort_t* __restrict__ JW, ushort_t* __restrict__ BW1, ushort_t* __restrict__ BW2,
                  ushort_t* __restrict__ JbdF, ushort_t* __restrict__ Bb2F, ushort_t* __restrict__ Bb2TF)
{
    const int b = blockIdx.x;
    if (b < 6144) {
        const int m = b >> 11;                       // 0:JW 1:BW1 2:BW2
        const int o = ((b & 2047) << 8) | threadIdx.x;
        const int ks = o & 31, n = (o >> 5) & 63, kt = o >> 11;
        const int k = (kt << 5) | ks;
        const int oi = k >> 7, h = k & 127;
        float val;
        if (m == 0)      val = Jw2[h * 4096 + n * 64 + oi] - Jw2[h * 4096 + oi * 64 + n];
        else if (m == 1) val = Bw2[h * 4096 + oi * 64 + n];
        else             val = Bw2[h * 4096 + n * 64 + oi];
        ushort_t* dst = (m == 0) ? JW : (m == 1) ? BW1 : BW2;
        dst[o] = f2bf(val);
    } else {
        for (int e = threadIdx.x; e < 12288; e += 256) {
            const int m = e >> 12, o = e & 4095;
            const int ks = o & 31, n = (o >> 5) & 63, kb = o >> 11;
            const int k = (kb << 5) | ks;
            float val; ushort_t* dst;
            if (m == 0)      { val = Jb2[n * 64 + k] - Jb2[k * 64 + n]; dst = JbdF; }
            else if (m == 1) { val = Bb2[k * 64 + n];                   dst = Bb2F; }
            else             { val = Bb2[n * 64 + k];                   dst = Bb2TF; }
            dst[o] = f2bf(val);
        }
    }
}

// ================= K1: scalar nets (H, D fwd+bwd), u-net, base = z + dt*pump =================
#define SCALAR_NET(W1, B1, W2, B2, W3, B3, GOUTP, STOREH)                             \
    do {                                                                              \
        for (int id = tid; id < NROWS * HID; id += NT) {                              \
            int r = id >> 7, h = id & (HID - 1);                                      \
            float acc = B1[h];                                                        \
            _Pragma("unroll")                                                         \
            for (int c = 0; c < DIM; ++c) acc += zs[r][c] * W1[c * HID + h];          \
            buf1[r][h] = acc; buf2[r][h] = siluf(acc);                                \
        }                                                                             \
        __syncthreads();                                                              \
        for (int id = tid; id < NROWS * HID; id += NT) {                              \
            int r = id >> 7, h = id & (HID - 1);                                      \
            float acc = B2[h];                                                        \
            _Pragma("unroll 8")                                                       \
            for (int c = 0; c < HID; ++c) acc += buf2[r][c] * W2[c * HID + h];        \
            buf3[r][h] = acc;                                                         \
        }                                                                             \
        __syncthreads();                                                              \
        {                                                                             \
            int r = tid >> 4, pp = tid & 15;                                          \
            float acc = 0.f;                                                          \
            _Pragma("unroll")                                                         \
            for (int c8 = 0; c8 < 8; ++c8) {                                          \
                int c = pp * 8 + c8;                                                  \
                acc += siluf(buf3[r][c]) * W3[c];                                     \
            }                                                                         \
            acc += __shfl_xor(acc, 1); acc += __shfl_xor(acc, 2);                     \
            acc += __shfl_xor(acc, 4); acc += __shfl_xor(acc, 8);                     \
            if (pp == 0) {                                                            \
                float a3 = acc + B3[0];                                               \
                if (STOREH) Hrow[r] = softplusf(a3);                                  \
                srow[r] = sigm(a3);                                                   \
            }                                                                         \
        }                                                                             \
        __syncthreads();                                                              \
        for (int id = tid; id < NROWS * HID; id += NT) {                              \
            int r = id >> 7, h = id & (HID - 1);                                      \
            buf3[r][h] = srow[r] * W3[h] * silup(buf3[r][h]);                         \
        }                                                                             \
        __syncthreads();                                                              \
        for (int id = tid; id < NROWS * HID; id += NT) {                              \
            int r = id >> 7, i = id & (HID - 1);                                      \
            float acc = 0.f;                                                          \
            _Pragma("unroll")                                                         \
            for (int c4 = 0; c4 < HID / 4; ++c4) {                                    \
                const float4 w4 = *(const float4*)&W2[i * HID + c4 * 4];              \
                const float4 d4 = *(const float4*)&buf3[r][c4 * 4];                   \
                acc += w4.x * d4.x + w4.y * d4.y + w4.z * d4.z + w4.w * d4.w;         \
            }                                                                         \
            buf2[r][i] = acc * silup(buf1[r][i]);                                     \
        }                                                                             \
        __syncthreads();                                                              \
        for (int id = tid; id < NROWS * DIM; id += NT) {                              \
            int r = id >> 6, k2 = id & (DIM - 1);                                     \
            float acc = 0.f;                                                          \
            _Pragma("unroll")                                                         \
            for (int c4 = 0; c4 < HID / 4; ++c4) {                                    \
                const float4 w4 = *(const float4*)&W1[k2 * HID + c4 * 4];             \
                const float4 d4 = *(const float4*)&buf2[r][c4 * 4];                   \
                acc += w4.x * d4.x + w4.y * d4.y + w4.z * d4.z + w4.w * d4.w;         \
            }                                                                         \
            GOUTP[(size_t)(r0 + r) * DIM + k2] = f2bf(acc);                           \
        }                                                                             \
        __syncthreads();                                                              \
    } while (0)

extern "C" __global__ __launch_bounds__(NT, 4)
void k1_kernel(const float* __restrict__ z,
               const float* __restrict__ Hw1, const float* __restrict__ Hb1,
               const float* __restrict__ Hw2, const float* __restrict__ Hb2,
               const float* __restrict__ Hw3, const float* __restrict__ Hb3,
               const float* __restrict__ Dw1, const float* __restrict__ Db1,
               const float* __restrict__ Dw2, const float* __restrict__ Db2,
               const float* __restrict__ Dw3, const float* __restrict__ Db3,
               const float* __restrict__ uw1, const float* __restrict__ ub1,
               const float* __restrict__ uw2, const float* __restrict__ ub2,
               const float* __restrict__ dtl, const float* __restrict__ etg,
               ushort_t* __restrict__ gHbf, ushort_t* __restrict__ gDbf,
               float* __restrict__ out)
{
    __shared__ __align__(16) float zs[NROWS][DIM];
    __shared__ __align__(16) float buf1[NROWS][HID];
    __shared__ __align__(16) float buf2[NROWS][HID];
    __shared__ __align__(16) float buf3[NROWS][HID];
    __shared__ __align__(16) float uv[NROWS][DIM];
    __shared__ float Hrow[NROWS];
    __shared__ float srow[NROWS];

    const int tid = threadIdx.x;
    const int r0 = blockIdx.x * NROWS;

    {
        const float4* zg = reinterpret_cast<const float4*>(z) + (size_t)r0 * (DIM / 4);
        reinterpret_cast<float4*>(&zs[0][0])[tid] = zg[tid];
    }
    __syncthreads();

    SCALAR_NET(Hw1, Hb1, Hw2, Hb2, Hw3, Hb3, gHbf, 1);
    SCALAR_NET(Dw1, Db1, Dw2, Db2, Dw3, Db3, gDbf, 0);

    // u-net layer1 (tanh) -> buf3
    for (int id = tid; id < NROWS * HID; id += NT) {
        int r = id >> 7, h = id & (HID - 1);
        float acc = ub1[h];
        #pragma unroll
        for (int c = 0; c < DIM; ++c) acc += zs[r][c] * uw1[c * HID + h];
        buf3[r][h] = tanhf(acc);
    }
    __syncthreads();
    // u layer2 -> uv
    for (int id = tid; id < NROWS * DIM; id += NT) {
        int r = id >> 6, k = id & (DIM - 1);
        float acc = ub2[k];
        #pragma unroll 8
        for (int c = 0; c < HID; ++c) acc += buf3[r][c] * uw2[c * DIM + k];
        uv[r][k] = acc;
    }
    __syncthreads();

    const float dt = 0.1f * sigm(dtl[0]);
    const float et = etg[0];
    for (int id = tid; id < NROWS * DIM; id += NT) {
        int r = id >> 6, c = id & (DIM - 1);
        float bs = zs[r][c] + dt * 0.1f * (et - Hrow[r]) * uv[r][c];
        out[(size_t)(r0 + r) * DIM + c] = bs;
    }
}

// ================= K2: heavy contractions as outer-product MFMA GEMMs =================
#define LOADHF(SRC)                                                                   \
    do {                                                                              \
        _Pragma("unroll")                                                             \
        for (int q4 = 0; q4 < 4; ++q4) {                                              \
            short8 s8a = *(const short8*)&SRC[rr0][q4 * 32 + (qq << 3)];              \
            short8 s8b = *(const short8*)&SRC[rr1][q4 * 32 + (qq << 3)];              \
            _Pragma("unroll")                                                         \
            for (int e = 0; e < 8; ++e) {                                             \
                hf0[q4 * 8 + e] = bf2f((ushort_t)s8a[e]);                             \
                hf1[q4 * 8 + e] = bf2f((ushort_t)s8b[e]);                             \
            }                                                                         \
        }                                                                             \
    } while (0)

#define GEMM_PASS(W, BF, G0, G1, A00, A01, A10, A11)                                  \
    do {                                                                              \
        const ushort_t* wpp = (W) + wbase;                                            \
        _Pragma("unroll 2")                                                           \
        for (int kc = 0; kc < 64; ++kc) {                                             \
            const float gj0 = bf2f((G0)[kc]);                                         \
            const float gj1 = bf2f((G1)[kc]);                                         \
            _Pragma("unroll")                                                         \
            for (int ki = 0; ki < 4; ++ki) {                                          \
                const int hb = ki * 8;                                                \
                union { unsigned int u[4]; short8 s; } a0, a1;                        \
                a0.u[0] = cvtpk(gj0 * hf0[hb + 0], gj0 * hf0[hb + 1]);                \
                a0.u[1] = cvtpk(gj0 * hf0[hb + 2], gj0 * hf0[hb + 3]);                \
                a0.u[2] = cvtpk(gj0 * hf0[hb + 4], gj0 * hf0[hb + 5]);                \
                a0.u[3] = cvtpk(gj0 * hf0[hb + 6], gj0 * hf0[hb + 7]);                \
                a1.u[0] = cvtpk(gj1 * hf1[hb + 0], gj1 * hf1[hb + 1]);                \
                a1.u[1] = cvtpk(gj1 * hf1[hb + 2], gj1 * hf1[hb + 3]);                \
                a1.u[2] = cvtpk(gj1 * hf1[hb + 4], gj1 * hf1[hb + 5]);                \
                a1.u[3] = cvtpk(gj1 * hf1[hb + 6], gj1 * hf1[hb + 7]);                \
                short8 b0 = *(const short8*)(wpp);                                    \
                short8 b1 = *(const short8*)(wpp + 512);                              \
                A00 = __builtin_amdgcn_mfma_f32_16x16x32_bf16(a0.s, b0, A00, 0, 0, 0);\
                A01 = __builtin_amdgcn_mfma_f32_16x16x32_bf16(a0.s, b1, A01, 0, 0, 0);\
                A10 = __builtin_amdgcn_mfma_f32_16x16x32_bf16(a1.s, b0, A10, 0, 0, 0);\
                A11 = __builtin_amdgcn_mfma_f32_16x16x32_bf16(a1.s, b1, A11, 0, 0, 0);\
                wpp += 2048;                                                          \
            }                                                                         \
        }                                                                             \
        _Pragma("unroll")                                                             \
        for (int kb = 0; kb < 2; ++kb) {                                              \
            short8 ab0 = *(const short8*)((G0) + kb * 32 + (qq << 3));                \
            short8 ab1 = *(const short8*)((G1) + kb * 32 + (qq << 3));                \
            const ushort_t* bp = (BF) + kb * 2048 + wbase;                            \
            short8 b0 = *(const short8*)(bp);                                         \
            short8 b1 = *(const short8*)(bp + 512);                                   \
            A00 = __builtin_amdgcn_mfma_f32_16x16x32_bf16(ab0, b0, A00, 0, 0, 0);     \
            A01 = __builtin_amdgcn_mfma_f32_16x16x32_bf16(ab0, b1, A01, 0, 0, 0);     \
            A10 = __builtin_amdgcn_mfma_f32_16x16x32_bf16(ab1, b0, A10, 0, 0, 0);     \
            A11 = __builtin_amdgcn_mfma_f32_16x16x32_bf16(ab1, b1, A11, 0, 0, 0);     \
        }                                                                             \
    } while (0)

extern "C" __global__ __launch_bounds__(256, 2)
void k2_kernel(const float* __restrict__ z,
               const float* __restrict__ Jw1, const float* __restrict__ Jb1,
               const float* __restrict__ Bw1, const float* __restrict__ Bb1,
               const float* __restrict__ dtl,
               const ushort_t* __restrict__ JW, const ushort_t* __restrict__ BW1,
               const ushort_t* __restrict__ BW2,
               const ushort_t* __restrict__ JbdF, const ushort_t* __restrict__ Bb2F,
               const ushort_t* __restrict__ Bb2TF,
               const ushort_t* __restrict__ gHbf, const ushort_t* __restrict__ gDbf,
               float* __restrict__ out)
{
    __shared__ __align__(16) float zs2[64][64];          // 16KB
    __shared__ __align__(16) ushort_t hJ2[64][128];      // 16KB
    __shared__ __align__(16) ushort_t hB2[64][128];      // 16KB
    __shared__ __align__(16) ushort_t gHb[64][72];       // 9KB (padded: 144B row, 16B mult)
    __shared__ __align__(16) ushort_t gDb[64][72];
    __shared__ __align__(16) ushort_t vb2[64][72];

    const int tid = threadIdx.x;
    const int r0 = blockIdx.x * 64;

    // stage z (64x64 f32) and gH/gD (64x64 bf16 -> padded LDS)
    {
        const float4* zg = reinterpret_cast<const float4*>(z) + (size_t)r0 * (DIM / 4);
        float4* zd = reinterpret_cast<float4*>(&zs2[0][0]);
        #pragma unroll
        for (int it = 0; it < 4; ++it) zd[it * 256 + tid] = zg[it * 256 + tid];
        const short8* gh = (const short8*)(gHbf + (size_t)r0 * 64);
        const short8* gd = (const short8*)(gDbf + (size_t)r0 * 64);
        #pragma unroll
        for (int it = 0; it < 2; ++it) {
            int i = it * 256 + tid;
            int row = i >> 3, s = i & 7;
            *(short8*)&gHb[row][s * 8] = gh[i];
            *(short8*)&gDb[row][s * 8] = gd[i];
        }
    }
    __syncthreads();

    // phase A: J/B layer 1 for 64 rows
    for (int id = tid; id < 64 * HID; id += 256) {
        int r = id >> 7, h = id & (HID - 1);
        float aJ = Jb1[h], aB = Bb1[h];
        #pragma unroll
        for (int c = 0; c < DIM; ++c) {
            float zv = zs2[r][c];
            aJ += zv * Jw1[c * HID + h];
            aB += zv * Bw1[c * HID + h];
        }
        hJ2[r][h] = f2bf(siluf(aJ));
        hB2[r][h] = f2bf(siluf(aB));
    }
    __syncthreads();

    // wave mapping: w = (rt2, ch2); lane = (qq, cl)
    const int lane = tid & 63;
    const int w = tid >> 6;
    const int rt2 = w & 1;         // row half (32 rows)
    const int ch2 = w >> 1;        // col half (32 cols)
    const int cl = lane & 15;
    const int qq = lane >> 4;
    const int rr0 = rt2 * 32 + cl;
    const int rr1 = rr0 + 16;
    const int wbase = (ch2 * 32 + cl) * 32 + (qq << 3);

    float hf0[32], hf1[32];
    f32x4 c00 = {0,0,0,0}, c01 = {0,0,0,0}, c10 = {0,0,0,0}, c11 = {0,0,0,0};
    f32x4 v00 = {0,0,0,0}, v01 = {0,0,0,0}, v10 = {0,0,0,0}, v11 = {0,0,0,0};
    f32x4 d00 = {0,0,0,0}, d01 = {0,0,0,0}, d10 = {0,0,0,0}, d11 = {0,0,0,0};

    // GEMM1: cons = (A - A^T) gH, A-op = gH (x) hJ
    LOADHF(hJ2);
    GEMM_PASS(JW, JbdF, &gHb[rr0][0], &gHb[rr1][0], c00, c01, c10, c11);

    // GEMM2: v = Bm^T gD, A-op = gD (x) hB
    LOADHF(hB2);
    GEMM_PASS(BW1, Bb2F, &gDb[rr0][0], &gDb[rr1][0], v00, v01, v10, v11);

    // write v (bf16) to LDS for GEMM3
    {
        #pragma unroll
        for (int rtt = 0; rtt < 2; ++rtt) {
            #pragma unroll
            for (int ct = 0; ct < 2; ++ct) {
                const f32x4 vv = (rtt == 0) ? (ct == 0 ? v00 : v01) : (ct == 0 ? v10 : v11);
                #pragma unroll
                for (int q = 0; q < 4; ++q) {
                    int row = rt2 * 32 + rtt * 16 + qq * 4 + q;
                    int col = ch2 * 32 + ct * 16 + cl;
                    vb2[row][col] = f2bf(vv[q]);
                }
            }
        }
    }
    __syncthreads();

    // GEMM3: diss = Bm v, A-op = v (x) hB (hf still holds hB)
    GEMM_PASS(BW2, Bb2TF, &vb2[rr0][0], &vb2[rr1][0], d00, d01, d10, d11);

    // epilogue: out = base + dt*(cons - diss)
    const float dt = 0.1f * sigm(dtl[0]);
    #pragma unroll
    for (int rtt = 0; rtt < 2; ++rtt) {
        #pragma unroll
        for (int ct = 0; ct < 2; ++ct) {
            const f32x4 cc = (rtt == 0) ? (ct == 0 ? c00 : c01) : (ct == 0 ? c10 : c11);
            const f32x4 dd = (rtt == 0) ? (ct == 0 ? d00 : d01) : (ct == 0 ? d10 : d11);
            #pragma unroll
            for (int q = 0; q < 4; ++q) {
                int row = r0 + rt2 * 32 + rtt * 16 + qq * 4 + q;
                int col = ch2 * 32 + ct * 16 + cl;
                size_t idx = (size_t)row * 64 + col;
                out[idx] = out[idx] + dt * (cc[q] - dd[q]);
            }
        }
    }
}

extern "C" void kernel_launch(void* const* d_in, const int* in_sizes, int n_in,
                              void* d_out, int out_size, void* d_ws, size_t ws_size,
                              hipStream_t stream) {
    const float* p[27];
    for (int i = 0; i < 27; ++i) p[i] = (const float*)d_in[i];
    // ws layout (ushort elements)
    ushort_t* JW    = (ushort_t*)d_ws;
    ushort_t* BW1   = JW + 524288;
    ushort_t* BW2   = BW1 + 524288;
    ushort_t* JbdF  = BW2 + 524288;
    ushort_t* Bb2F  = JbdF + 4096;
    ushort_t* Bb2TF = Bb2F + 4096;
    ushort_t* gHbf  = Bb2TF + 4096;
    ushort_t* gDbf  = gHbf + (size_t)16384 * 64;

    hipLaunchKernelGGL(prep2_kernel, dim3(6145), dim3(256), 0, stream,
                       p[15], p[16], p[19], p[20], JW, BW1, BW2, JbdF, Bb2F, Bb2TF);

    const int batch = in_sizes[0] / DIM;
    hipLaunchKernelGGL(k1_kernel, dim3(batch / NROWS), dim3(NT), 0, stream,
                       p[0],
                       p[1], p[2], p[3], p[4], p[5], p[6],
                       p[7], p[8], p[9], p[10], p[11], p[12],
                       p[21], p[22], p[23], p[24],
                       p[25], p[26],
                       gHbf, gDbf, (float*)d_out);

    hipLaunchKernelGGL(k2_kernel, dim3(batch / 64), dim3(256), 0, stream,
                       p[0], p[13], p[14], p[17], p[18], p[25],
                       JW, BW1, BW2, JbdF, Bb2F, Bb2TF, gHbf, gDbf,
                       (float*)d_out);
}

// Round 4
// 470.004 us; speedup vs baseline: 2.6226x; 1.2907x over previous
//
#include <hip/hip_runtime.h>

#define DIM 64
#define HID 128
#define NROWS 16
#define NT 256

typedef __attribute__((ext_vector_type(8))) short short8;
typedef __attribute__((ext_vector_type(4))) float f32x4;
typedef unsigned short ushort_t;

__device__ __forceinline__ float sigm(float x) { return 1.f / (1.f + __expf(-x)); }
__device__ __forceinline__ float siluf(float x) { return x * sigm(x); }
__device__ __forceinline__ float silup(float x) { float s = sigm(x); return s + x * s * (1.f - s); }
__device__ __forceinline__ float softplusf(float x) {
    if (x > 20.f) return x;
    return log1pf(__expf(x));
}
__device__ __forceinline__ ushort_t f2bf(float f) {
    union { float f; unsigned int u; } v; v.f = f;
    unsigned int r = v.u + 0x7fffu + ((v.u >> 16) & 1u);
    return (ushort_t)(r >> 16);
}
__device__ __forceinline__ float bf2f(ushort_t u) {
    union { unsigned int u; float f; } v; v.u = ((unsigned int)u) << 16;
    return v.f;
}
__device__ __forceinline__ unsigned int cvtpk(float lo, float hi) {
    unsigned int r;
    asm("v_cvt_pk_bf16_f32 %0, %1, %2" : "=v"(r) : "v"(lo), "v"(hi));
    return r;
}

// ================= prep: build frag-layout weight matrices in ws =================
// Layout: W'[(kt*64 + n)*32 + ks], k = kt*32+ks. For JW/BW2: k=(j,h) => j=k>>7,h=k&127, n=i.
// For BW1: k=(i,h), n=j.
extern "C" __global__ __launch_bounds__(256)
void prep2_kernel(const float* __restrict__ Jw2, const float* __restrict__ Jb2,
                  const float* __restrict__ Bw2, const float* __restrict__ Bb2,
                  ushort_t* __restrict__ JW, ushort_t* __restrict__ BW1, ushort_t* __restrict__ BW2,
                  ushort_t* __restrict__ JbdF, ushort_t* __restrict__ Bb2F, ushort_t* __restrict__ Bb2TF)
{
    const int b = blockIdx.x;
    if (b < 6144) {
        const int m = b >> 11;                       // 0:JW 1:BW1 2:BW2
        const int o = ((b & 2047) << 8) | threadIdx.x;
        const int ks = o & 31, n = (o >> 5) & 63, kt = o >> 11;
        const int k = (kt << 5) | ks;
        const int oi = k >> 7, h = k & 127;
        float val;
        if (m == 0)      val = Jw2[h * 4096 + n * 64 + oi] - Jw2[h * 4096 + oi * 64 + n];
        else if (m == 1) val = Bw2[h * 4096 + oi * 64 + n];
        else             val = Bw2[h * 4096 + n * 64 + oi];
        ushort_t* dst = (m == 0) ? JW : (m == 1) ? BW1 : BW2;
        dst[o] = f2bf(val);
    } else {
        for (int e = threadIdx.x; e < 12288; e += 256) {
            const int m = e >> 12, o = e & 4095;
            const int ks = o & 31, n = (o >> 5) & 63, kb = o >> 11;
            const int k = (kb << 5) | ks;
            float val; ushort_t* dst;
            if (m == 0)      { val = Jb2[n * 64 + k] - Jb2[k * 64 + n]; dst = JbdF; }
            else if (m == 1) { val = Bb2[k * 64 + n];                   dst = Bb2F; }
            else             { val = Bb2[n * 64 + k];                   dst = Bb2TF; }
            dst[o] = f2bf(val);
        }
    }
}

// ================= K1: scalar nets (H, D fwd+bwd), u-net, base = z + dt*pump =================
#define SCALAR_NET(W1, B1, W2, B2, W3, B3, GOUTP, STOREH)                             \
    do {                                                                              \
        for (int id = tid; id < NROWS * HID; id += NT) {                              \
            int r = id >> 7, h = id & (HID - 1);                                      \
            float acc = B1[h];                                                        \
            _Pragma("unroll")                                                         \
            for (int c = 0; c < DIM; ++c) acc += zs[r][c] * W1[c * HID + h];          \
            buf1[r][h] = acc; buf2[r][h] = siluf(acc);                                \
        }                                                                             \
        __syncthreads();                                                              \
        for (int id = tid; id < NROWS * HID; id += NT) {                              \
            int r = id >> 7, h = id & (HID - 1);                                      \
            float acc = B2[h];                                                        \
            _Pragma("unroll 8")                                                       \
            for (int c = 0; c < HID; ++c) acc += buf2[r][c] * W2[c * HID + h];        \
            buf3[r][h] = acc;                                                         \
        }                                                                             \
        __syncthreads();                                                              \
        {                                                                             \
            int r = tid >> 4, pp = tid & 15;                                          \
            float acc = 0.f;                                                          \
            _Pragma("unroll")                                                         \
            for (int c8 = 0; c8 < 8; ++c8) {                                          \
                int c = pp * 8 + c8;                                                  \
                acc += siluf(buf3[r][c]) * W3[c];                                     \
            }                                                                         \
            acc += __shfl_xor(acc, 1); acc += __shfl_xor(acc, 2);                     \
            acc += __shfl_xor(acc, 4); acc += __shfl_xor(acc, 8);                     \
            if (pp == 0) {                                                            \
                float a3 = acc + B3[0];                                               \
                if (STOREH) Hrow[r] = softplusf(a3);                                  \
                srow[r] = sigm(a3);                                                   \
            }                                                                         \
        }                                                                             \
        __syncthreads();                                                              \
        for (int id = tid; id < NROWS * HID; id += NT) {                              \
            int r = id >> 7, h = id & (HID - 1);                                      \
            buf3[r][h] = srow[r] * W3[h] * silup(buf3[r][h]);                         \
        }                                                                             \
        __syncthreads();                                                              \
        for (int id = tid; id < NROWS * HID; id += NT) {                              \
            int r = id >> 7, i = id & (HID - 1);                                      \
            float acc = 0.f;                                                          \
            _Pragma("unroll")                                                         \
            for (int c4 = 0; c4 < HID / 4; ++c4) {                                    \
                const float4 w4 = *(const float4*)&W2[i * HID + c4 * 4];              \
                const float4 d4 = *(const float4*)&buf3[r][c4 * 4];                   \
                acc += w4.x * d4.x + w4.y * d4.y + w4.z * d4.z + w4.w * d4.w;         \
            }                                                                         \
            buf2[r][i] = acc * silup(buf1[r][i]);                                     \
        }                                                                             \
        __syncthreads();                                                              \
        for (int id = tid; id < NROWS * DIM; id += NT) {                              \
            int r = id >> 6, k2 = id & (DIM - 1);                                     \
            float acc = 0.f;                                                          \
            _Pragma("unroll")                                                         \
            for (int c4 = 0; c4 < HID / 4; ++c4) {                                    \
                const float4 w4 = *(const float4*)&W1[k2 * HID + c4 * 4];             \
                const float4 d4 = *(const float4*)&buf2[r][c4 * 4];                   \
                acc += w4.x * d4.x + w4.y * d4.y + w4.z * d4.z + w4.w * d4.w;         \
            }                                                                         \
            GOUTP[(size_t)(r0 + r) * DIM + k2] = f2bf(acc);                           \
        }                                                                             \
        __syncthreads();                                                              \
    } while (0)

extern "C" __global__ __launch_bounds__(NT, 2)
void k1_kernel(const float* __restrict__ z,
               const float* __restrict__ Hw1, const float* __restrict__ Hb1,
               const float* __restrict__ Hw2, const float* __restrict__ Hb2,
               const float* __restrict__ Hw3, const float* __restrict__ Hb3,
               const float* __restrict__ Dw1, const float* __restrict__ Db1,
               const float* __restrict__ Dw2, const float* __restrict__ Db2,
               const float* __restrict__ Dw3, const float* __restrict__ Db3,
               const float* __restrict__ uw1, const float* __restrict__ ub1,
               const float* __restrict__ uw2, const float* __restrict__ ub2,
               const float* __restrict__ dtl, const float* __restrict__ etg,
               ushort_t* __restrict__ gHbf, ushort_t* __restrict__ gDbf,
               float* __restrict__ out)
{
    __shared__ __align__(16) float zs[NROWS][DIM];
    __shared__ __align__(16) float buf1[NROWS][HID];
    __shared__ __align__(16) float buf2[NROWS][HID];
    __shared__ __align__(16) float buf3[NROWS][HID];
    __shared__ __align__(16) float uv[NROWS][DIM];
    __shared__ float Hrow[NROWS];
    __shared__ float srow[NROWS];

    const int tid = threadIdx.x;
    const int r0 = blockIdx.x * NROWS;

    {
        const float4* zg = reinterpret_cast<const float4*>(z) + (size_t)r0 * (DIM / 4);
        reinterpret_cast<float4*>(&zs[0][0])[tid] = zg[tid];
    }
    __syncthreads();

    SCALAR_NET(Hw1, Hb1, Hw2, Hb2, Hw3, Hb3, gHbf, 1);
    SCALAR_NET(Dw1, Db1, Dw2, Db2, Dw3, Db3, gDbf, 0);

    // u-net layer1 (tanh) -> buf3
    for (int id = tid; id < NROWS * HID; id += NT) {
        int r = id >> 7, h = id & (HID - 1);
        float acc = ub1[h];
        #pragma unroll
        for (int c = 0; c < DIM; ++c) acc += zs[r][c] * uw1[c * HID + h];
        buf3[r][h] = tanhf(acc);
    }
    __syncthreads();
    // u layer2 -> uv
    for (int id = tid; id < NROWS * DIM; id += NT) {
        int r = id >> 6, k = id & (DIM - 1);
        float acc = ub2[k];
        #pragma unroll 8
        for (int c = 0; c < HID; ++c) acc += buf3[r][c] * uw2[c * DIM + k];
        uv[r][k] = acc;
    }
    __syncthreads();

    const float dt = 0.1f * sigm(dtl[0]);
    const float et = etg[0];
    for (int id = tid; id < NROWS * DIM; id += NT) {
        int r = id >> 6, c = id & (DIM - 1);
        float bs = zs[r][c] + dt * 0.1f * (et - Hrow[r]) * uv[r][c];
        out[(size_t)(r0 + r) * DIM + c] = bs;
    }
}

// ================= K2: heavy contractions as outer-product MFMA GEMMs =================
// 512 threads = 8 waves: rt = w&3 (16-row frag), ch = w>>2 (32-col half)
#define LOADHF(SRC)                                                                   \
    do {                                                                              \
        _Pragma("unroll")                                                             \
        for (int q4 = 0; q4 < 4; ++q4) {                                              \
            short8 s8 = *(const short8*)&SRC[rr][q4 * 32 + (qq << 3)];                \
            _Pragma("unroll")                                                         \
            for (int e = 0; e < 8; ++e) hf[q4 * 8 + e] = bf2f((ushort_t)s8[e]);       \
        }                                                                             \
    } while (0)

#define GEMM_PASS(W, BF, G, A0, A1)                                                   \
    do {                                                                              \
        const ushort_t* wpp = (W) + wbase;                                            \
        _Pragma("unroll 2")                                                           \
        for (int kc = 0; kc < 64; ++kc) {                                             \
            const float gj = bf2f((G)[kc]);                                           \
            _Pragma("unroll")                                                         \
            for (int ki = 0; ki < 4; ++ki) {                                          \
                const int hb = ki * 8;                                                \
                union { unsigned int u[4]; short8 s; } a;                             \
                a.u[0] = cvtpk(gj * hf[hb + 0], gj * hf[hb + 1]);                     \
                a.u[1] = cvtpk(gj * hf[hb + 2], gj * hf[hb + 3]);                     \
                a.u[2] = cvtpk(gj * hf[hb + 4], gj * hf[hb + 5]);                     \
                a.u[3] = cvtpk(gj * hf[hb + 6], gj * hf[hb + 7]);                     \
                short8 b0 = *(const short8*)(wpp);                                    \
                short8 b1 = *(const short8*)(wpp + 512);                              \
                A0 = __builtin_amdgcn_mfma_f32_16x16x32_bf16(a.s, b0, A0, 0, 0, 0);   \
                A1 = __builtin_amdgcn_mfma_f32_16x16x32_bf16(a.s, b1, A1, 0, 0, 0);   \
                wpp += 2048;                                                          \
            }                                                                         \
        }                                                                             \
        _Pragma("unroll")                                                             \
        for (int kb = 0; kb < 2; ++kb) {                                              \
            short8 ab = *(const short8*)((G) + kb * 32 + (qq << 3));                  \
            const ushort_t* bp = (BF) + kb * 2048 + wbase;                            \
            short8 b0 = *(const short8*)(bp);                                         \
            short8 b1 = *(const short8*)(bp + 512);                                   \
            A0 = __builtin_amdgcn_mfma_f32_16x16x32_bf16(ab, b0, A0, 0, 0, 0);        \
            A1 = __builtin_amdgcn_mfma_f32_16x16x32_bf16(ab, b1, A1, 0, 0, 0);        \
        }                                                                             \
    } while (0)

extern "C" __global__ __launch_bounds__(512, 2)
void k2_kernel(const float* __restrict__ z,
               const float* __restrict__ Jw1, const float* __restrict__ Jb1,
               const float* __restrict__ Bw1, const float* __restrict__ Bb1,
               const float* __restrict__ dtl,
               const ushort_t* __restrict__ JW, const ushort_t* __restrict__ BW1,
               const ushort_t* __restrict__ BW2,
               const ushort_t* __restrict__ JbdF, const ushort_t* __restrict__ Bb2F,
               const ushort_t* __restrict__ Bb2TF,
               const ushort_t* __restrict__ gHbf, const ushort_t* __restrict__ gDbf,
               float* __restrict__ out)
{
    __shared__ __align__(16) float zs2[64][64];          // 16KB
    __shared__ __align__(16) ushort_t hJ2[64][128];      // 16KB
    __shared__ __align__(16) ushort_t hB2[64][128];      // 16KB
    __shared__ __align__(16) ushort_t gHb[64][72];       // 9KB (144B row, 16B mult)
    __shared__ __align__(16) ushort_t gDb[64][72];
    __shared__ __align__(16) ushort_t vb2[64][72];

    const int tid = threadIdx.x;   // 0..511
    const int r0 = blockIdx.x * 64;

    // stage z (64x64 f32) and gH/gD (64x64 bf16 -> padded LDS)
    {
        const float4* zg = reinterpret_cast<const float4*>(z) + (size_t)r0 * (DIM / 4);
        float4* zd = reinterpret_cast<float4*>(&zs2[0][0]);
        zd[tid] = zg[tid];
        zd[512 + tid] = zg[512 + tid];
        const short8* gh = (const short8*)(gHbf + (size_t)r0 * 64);
        const short8* gd = (const short8*)(gDbf + (size_t)r0 * 64);
        int row = tid >> 3, s = tid & 7;
        *(short8*)&gHb[row][s * 8] = gh[tid];
        *(short8*)&gDb[row][s * 8] = gd[tid];
    }
    __syncthreads();

    // phase A: J/B layer 1 for 64 rows
    for (int id = tid; id < 64 * HID; id += 512) {
        int r = id >> 7, h = id & (HID - 1);
        float aJ = Jb1[h], aB = Bb1[h];
        #pragma unroll
        for (int c = 0; c < DIM; ++c) {
            float zv = zs2[r][c];
            aJ += zv * Jw1[c * HID + h];
            aB += zv * Bw1[c * HID + h];
        }
        hJ2[r][h] = f2bf(siluf(aJ));
        hB2[r][h] = f2bf(siluf(aB));
    }
    __syncthreads();

    const int lane = tid & 63;
    const int w = tid >> 6;        // 0..7
    const int rt = w & 3;          // 16-row fragment
    const int ch = w >> 2;         // 32-col half
    const int cl = lane & 15;
    const int qq = lane >> 4;
    const int rr = rt * 16 + cl;
    const int wbase = (ch * 32 + cl) * 32 + (qq << 3);

    float hf[32];
    f32x4 c0 = {0,0,0,0}, c1 = {0,0,0,0};
    f32x4 v0 = {0,0,0,0}, v1 = {0,0,0,0};
    f32x4 d0 = {0,0,0,0}, d1 = {0,0,0,0};

    // GEMM1: cons = (A - A^T) gH, A-op = gH (x) hJ
    LOADHF(hJ2);
    GEMM_PASS(JW, JbdF, &gHb[rr][0], c0, c1);

    // GEMM2: v = Bm^T gD, A-op = gD (x) hB
    LOADHF(hB2);
    GEMM_PASS(BW1, Bb2F, &gDb[rr][0], v0, v1);

    // write v (bf16) to LDS for GEMM3
    #pragma unroll
    for (int ct = 0; ct < 2; ++ct) {
        const f32x4 vv = ct ? v1 : v0;
        #pragma unroll
        for (int q = 0; q < 4; ++q)
            vb2[rt * 16 + qq * 4 + q][ch * 32 + ct * 16 + cl] = f2bf(vv[q]);
    }
    __syncthreads();

    // GEMM3: diss = Bm v, A-op = v (x) hB (hf still holds hB)
    GEMM_PASS(BW2, Bb2TF, &vb2[rr][0], d0, d1);

    // epilogue: out = base + dt*(cons - diss)
    const float dt = 0.1f * sigm(dtl[0]);
    #pragma unroll
    for (int ct = 0; ct < 2; ++ct) {
        const f32x4 cc = ct ? c1 : c0;
        const f32x4 dd = ct ? d1 : d0;
        #pragma unroll
        for (int q = 0; q < 4; ++q) {
            int row = r0 + rt * 16 + qq * 4 + q;
            int col = ch * 32 + ct * 16 + cl;
            size_t idx = (size_t)row * 64 + col;
            out[idx] = out[idx] + dt * (cc[q] - dd[q]);
        }
    }
}

extern "C" void kernel_launch(void* const* d_in, const int* in_sizes, int n_in,
                              void* d_out, int out_size, void* d_ws, size_t ws_size,
                              hipStream_t stream) {
    const float* p[27];
    for (int i = 0; i < 27; ++i) p[i] = (const float*)d_in[i];
    // ws layout (ushort elements)
    ushort_t* JW    = (ushort_t*)d_ws;
    ushort_t* BW1   = JW + 524288;
    ushort_t* BW2   = BW1 + 524288;
    ushort_t* JbdF  = BW2 + 524288;
    ushort_t* Bb2F  = JbdF + 4096;
    ushort_t* Bb2TF = Bb2F + 4096;
    ushort_t* gHbf  = Bb2TF + 4096;
    ushort_t* gDbf  = gHbf + (size_t)16384 * 64;

    hipLaunchKernelGGL(prep2_kernel, dim3(6145), dim3(256), 0, stream,
                       p[15], p[16], p[19], p[20], JW, BW1, BW2, JbdF, Bb2F, Bb2TF);

    const int batch = in_sizes[0] / DIM;
    hipLaunchKernelGGL(k1_kernel, dim3(batch / NROWS), dim3(NT), 0, stream,
                       p[0],
                       p[1], p[2], p[3], p[4], p[5], p[6],
                       p[7], p[8], p[9], p[10], p[11], p[12],
                       p[21], p[22], p[23], p[24],
                       p[25], p[26],
                       gHbf, gDbf, (float*)d_out);

    hipLaunchKernelGGL(k2_kernel, dim3(batch / 64), dim3(512), 0, stream,
                       p[0], p[13], p[14], p[17], p[18], p[25],
                       JW, BW1, BW2, JbdF, Bb2F, Bb2TF, gHbf, gDbf,
                       (float*)d_out);
}

// Round 6
// 248.415 us; speedup vs baseline: 4.9620x; 1.8920x over previous
//
#include <hip/hip_runtime.h>

#define DIM 64
#define HID 128

typedef __attribute__((ext_vector_type(8))) short short8;
typedef __attribute__((ext_vector_type(4))) float f32x4;
typedef __attribute__((ext_vector_type(2))) float f32x2;
typedef unsigned short ushort_t;

#define MFMA(A, B, C) __builtin_amdgcn_mfma_f32_16x16x32_bf16((A), (B), (C), 0, 0, 0)

__device__ __forceinline__ float sigm(float x) { return 1.f / (1.f + __expf(-x)); }
__device__ __forceinline__ float siluf(float x) { return x * sigm(x); }
__device__ __forceinline__ float silup(float x) { float s = sigm(x); return s + x * s * (1.f - s); }
__device__ __forceinline__ float softplusf(float x) {
    if (x > 20.f) return x;
    return log1pf(__expf(x));
}
__device__ __forceinline__ ushort_t f2bf(float f) {
    union { float f; unsigned int u; } v; v.f = f;
    unsigned int r = v.u + 0x7fffu + ((v.u >> 16) & 1u);
    return (ushort_t)(r >> 16);
}
__device__ __forceinline__ float bf2f(ushort_t u) {
    union { unsigned int u; float f; } v; v.u = ((unsigned int)u) << 16;
    return v.f;
}
__device__ __forceinline__ unsigned int cvtpk(float lo, float hi) {
    unsigned int r;
    asm("v_cvt_pk_bf16_f32 %0, %1, %2" : "=v"(r) : "v"(lo), "v"(hi));
    return r;
}

// SWF offsets (ushort elems)
#define OFF_HW1F  0
#define OFF_HW2F  8192
#define OFF_HW2TF 24576
#define OFF_HW1TF 40960
#define OFF_DW1F  49152
#define OFF_DW2F  57344
#define OFF_DW2TF 73728
#define OFF_DW1TF 90112
#define OFF_UW1F  98304
#define OFF_UW2F  106496
#define OFF_JW1F  114688
#define OFF_BW1F  122880
#define SWF_TOTAL 131072

// ================= prep: frag-layout bf16 weight matrices =================
extern "C" __global__ __launch_bounds__(256)
void prep3_kernel(const float* __restrict__ Jw2, const float* __restrict__ Jb2,
                  const float* __restrict__ Bw2, const float* __restrict__ Bb2,
                  const float* __restrict__ Hw1, const float* __restrict__ Hw2,
                  const float* __restrict__ Dw1, const float* __restrict__ Dw2,
                  const float* __restrict__ uw1, const float* __restrict__ uw2,
                  const float* __restrict__ Jw1, const float* __restrict__ Bw1,
                  ushort_t* __restrict__ JW, ushort_t* __restrict__ BW1, ushort_t* __restrict__ BW2,
                  ushort_t* __restrict__ JbdF, ushort_t* __restrict__ Bb2F, ushort_t* __restrict__ Bb2TF,
                  ushort_t* __restrict__ SWF)
{
    const int b = blockIdx.x;
    if (b < 6144) {
        const int m = b >> 11;                       // 0:JW 1:BW1 2:BW2
        const int o = ((b & 2047) << 8) | threadIdx.x;
        const int ks = o & 31, n = (o >> 5) & 63, kt = o >> 11;
        const int k = (kt << 5) | ks;
        const int oi = k >> 7, h = k & 127;
        float val;
        if (m == 0)      val = Jw2[h * 4096 + n * 64 + oi] - Jw2[h * 4096 + oi * 64 + n];
        else if (m == 1) val = Bw2[h * 4096 + oi * 64 + n];
        else             val = Bw2[h * 4096 + n * 64 + oi];
        ushort_t* dst = (m == 0) ? JW : (m == 1) ? BW1 : BW2;
        dst[o] = f2bf(val);
    } else if (b == 6144) {
        for (int e = threadIdx.x; e < 12288; e += 256) {
            const int m = e >> 12, o = e & 4095;
            const int ks = o & 31, n = (o >> 5) & 63, kb = o >> 11;
            const int k = (kb << 5) | ks;
            float val; ushort_t* dst;
            if (m == 0)      { val = Jb2[n * 64 + k] - Jb2[k * 64 + n]; dst = JbdF; }
            else if (m == 1) { val = Bb2[k * 64 + n];                   dst = Bb2F; }
            else             { val = Bb2[n * 64 + k];                   dst = Bb2TF; }
            dst[o] = f2bf(val);
        }
    } else {
        const int e = (b - 6145) * 256 + threadIdx.x;    // 0..131071
        float val = 0.f;
        if (e < 98304) {
            const int net = e / 49152;
            const int o = e - net * 49152;
            const float* W1s = net ? Dw1 : Hw1;
            const float* W2s = net ? Dw2 : Hw2;
            if (o < 8192) {                 // W1f
                int ks = o & 31, n = (o >> 5) & 127, kt = o >> 12;
                val = W1s[(kt * 32 + ks) * 128 + n];
            } else if (o < 24576) {         // W2f
                int o2 = o - 8192;
                int ks = o2 & 31, n = (o2 >> 5) & 127, kt = o2 >> 12;
                val = W2s[(kt * 32 + ks) * 128 + n];
            } else if (o < 40960) {         // W2Tf
                int o3 = o - 24576;
                int ks = o3 & 31, n = (o3 >> 5) & 127, kt = o3 >> 12;
                val = W2s[n * 128 + kt * 32 + ks];
            } else {                        // W1Tf
                int o4 = o - 40960;
                int ks = o4 & 31, n = (o4 >> 5) & 63, kt = o4 >> 11;
                val = W1s[n * 128 + kt * 32 + ks];
            }
        } else if (e < 106496) {            // UW1f
            int o = e - 98304;
            int ks = o & 31, n = (o >> 5) & 127, kt = o >> 12;
            val = uw1[(kt * 32 + ks) * 128 + n];
        } else if (e < 114688) {            // UW2f
            int o = e - 106496;
            int ks = o & 31, n = (o >> 5) & 63, kt = o >> 11;
            val = uw2[(kt * 32 + ks) * 64 + n];
        } else if (e < 122880) {            // JW1f
            int o = e - 114688;
            int ks = o & 31, n = (o >> 5) & 127, kt = o >> 12;
            val = Jw1[(kt * 32 + ks) * 128 + n];
        } else {                            // BW1f
            int o = e - 122880;
            int ks = o & 31, n = (o >> 5) & 127, kt = o >> 12;
            val = Bw1[(kt * 32 + ks) * 128 + n];
        }
        SWF[e] = f2bf(val);
    }
}

// ================= K1: scalar nets + u-net via MFMA =================
__device__ __forceinline__ void scalar_net(
    int tid, int r0,
    const ushort_t* zbp, ushort_t* S1, ushort_t* S2, ushort_t* S3,
    float* yacc, float* srow, float* Hrow,
    const ushort_t* W1f, const ushort_t* W2f, const ushort_t* W2Tf, const ushort_t* W1Tf,
    const float* B1, const float* B2, const float* W3, const float* B3,
    ushort_t* gOut, int storeH)
{
    const int lane = tid & 63, w = tid >> 6;
    const int mt = w & 3, nh = w >> 2;
    const int cl = lane & 15, qq = lane >> 4;
    const int arow = mt * 16 + cl;
    const int crow = mt * 16 + qq * 4;

    // ---- L1 ----
    {
        short8 a0 = *(const short8*)&zbp[arow * 72 + (qq << 3)];
        short8 a1 = *(const short8*)&zbp[arow * 72 + 32 + (qq << 3)];
        #pragma unroll
        for (int nt = 0; nt < 4; ++nt) {
            int n = nh * 64 + nt * 16 + cl;
            f32x4 acc = {0.f, 0.f, 0.f, 0.f};
            short8 b0 = *(const short8*)&W1f[(n << 5) + (qq << 3)];
            short8 b1 = *(const short8*)&W1f[((128 + n) << 5) + (qq << 3)];
            acc = MFMA(a0, b0, acc); acc = MFMA(a1, b1, acc);
            float bv = B1[n];
            #pragma unroll
            for (int q = 0; q < 4; ++q) {
                float aa = acc[q] + bv;
                S1[(crow + q) * 136 + n] = f2bf(siluf(aa));
                S2[(crow + q) * 136 + n] = f2bf(silup(aa));
            }
        }
    }
    __syncthreads();
    // ---- L2 + y partial ----
    {
        short8 a[4];
        #pragma unroll
        for (int kt = 0; kt < 4; ++kt)
            a[kt] = *(const short8*)&S1[arow * 136 + kt * 32 + (qq << 3)];
        float yp[4] = {0.f, 0.f, 0.f, 0.f};
        #pragma unroll
        for (int nt = 0; nt < 4; ++nt) {
            int n = nh * 64 + nt * 16 + cl;
            f32x4 acc = {0.f, 0.f, 0.f, 0.f};
            #pragma unroll
            for (int kt = 0; kt < 4; ++kt) {
                short8 bb = *(const short8*)&W2f[((kt * 128 + n) << 5) + (qq << 3)];
                acc = MFMA(a[kt], bb, acc);
            }
            float bv = B2[n], w3v = W3[n];
            #pragma unroll
            for (int q = 0; q < 4; ++q) {
                float a2 = acc[q] + bv;
                yp[q] += siluf(a2) * w3v;
                S3[(crow + q) * 136 + n] = f2bf(w3v * silup(a2));
            }
        }
        #pragma unroll
        for (int q = 0; q < 4; ++q) {
            float p = yp[q];
            p += __shfl_xor(p, 1); p += __shfl_xor(p, 2);
            p += __shfl_xor(p, 4); p += __shfl_xor(p, 8);
            if (cl == 0) atomicAdd(&yacc[crow + q], p);
        }
    }
    __syncthreads();
    if (tid < 64) {
        float a3 = yacc[tid] + B3[0];
        srow[tid] = sigm(a3);
        if (storeH) Hrow[tid] = softplusf(a3);
        yacc[tid] = 0.f;
    }
    __syncthreads();
    // ---- bwd1: da1 = (da2~ @ W2T) * s1p -> S1 ----
    {
        short8 a[4];
        #pragma unroll
        for (int kt = 0; kt < 4; ++kt)
            a[kt] = *(const short8*)&S3[arow * 136 + kt * 32 + (qq << 3)];
        #pragma unroll
        for (int nt = 0; nt < 4; ++nt) {
            int n = nh * 64 + nt * 16 + cl;
            f32x4 acc = {0.f, 0.f, 0.f, 0.f};
            #pragma unroll
            for (int kt = 0; kt < 4; ++kt) {
                short8 bb = *(const short8*)&W2Tf[((kt * 128 + n) << 5) + (qq << 3)];
                acc = MFMA(a[kt], bb, acc);
            }
            #pragma unroll
            for (int q = 0; q < 4; ++q) {
                float sp = bf2f(S2[(crow + q) * 136 + n]);
                S1[(crow + q) * 136 + n] = f2bf(acc[q] * sp);
            }
        }
    }
    __syncthreads();
    // ---- bwd2: g = srow * (da1 @ W1T) -> global bf16 ----
    {
        short8 a[4];
        #pragma unroll
        for (int kt = 0; kt < 4; ++kt)
            a[kt] = *(const short8*)&S1[arow * 136 + kt * 32 + (qq << 3)];
        #pragma unroll
        for (int ntl = 0; ntl < 2; ++ntl) {
            int n = nh * 32 + ntl * 16 + cl;
            f32x4 acc = {0.f, 0.f, 0.f, 0.f};
            #pragma unroll
            for (int kt = 0; kt < 4; ++kt) {
                short8 bb = *(const short8*)&W1Tf[((kt * 64 + n) << 5) + (qq << 3)];
                acc = MFMA(a[kt], bb, acc);
            }
            #pragma unroll
            for (int q = 0; q < 4; ++q) {
                int row = crow + q;
                gOut[(size_t)(r0 + row) * 64 + n] = f2bf(srow[row] * acc[q]);
            }
        }
    }
    __syncthreads();
}

extern "C" __global__ __launch_bounds__(512, 4)
void k1_kernel(const float* __restrict__ z,
               const float* __restrict__ Hb1, const float* __restrict__ Hb2,
               const float* __restrict__ Hw3, const float* __restrict__ Hb3,
               const float* __restrict__ Db1, const float* __restrict__ Db2,
               const float* __restrict__ Dw3, const float* __restrict__ Db3,
               const float* __restrict__ ub1, const float* __restrict__ ub2,
               const float* __restrict__ dtl, const float* __restrict__ etg,
               const ushort_t* __restrict__ SWF,
               ushort_t* __restrict__ gHbf, ushort_t* __restrict__ gDbf,
               float* __restrict__ out)
{
    __shared__ __align__(16) ushort_t zb[64][72];
    __shared__ __align__(16) ushort_t S1[64][136];
    __shared__ __align__(16) ushort_t S2[64][136];
    __shared__ __align__(16) ushort_t S3[64][136];
    __shared__ float yacc[64];
    __shared__ float srow[64];
    __shared__ float Hrow[64];

    const int tid = threadIdx.x;
    const int r0 = blockIdx.x * 64;

    {
        const float4* zg = (const float4*)(z + (size_t)r0 * 64);
        #pragma unroll
        for (int it = 0; it < 2; ++it) {
            int i = it * 512 + tid;
            float4 v = zg[i];
            int row = i >> 4, c4 = (i & 15) * 4;
            zb[row][c4 + 0] = f2bf(v.x); zb[row][c4 + 1] = f2bf(v.y);
            zb[row][c4 + 2] = f2bf(v.z); zb[row][c4 + 3] = f2bf(v.w);
        }
        if (tid < 64) yacc[tid] = 0.f;
    }
    __syncthreads();

    scalar_net(tid, r0, &zb[0][0], &S1[0][0], &S2[0][0], &S3[0][0], yacc, srow, Hrow,
               SWF + OFF_HW1F, SWF + OFF_HW2F, SWF + OFF_HW2TF, SWF + OFF_HW1TF,
               Hb1, Hb2, Hw3, Hb3, gHbf, 1);
    scalar_net(tid, r0, &zb[0][0], &S1[0][0], &S2[0][0], &S3[0][0], yacc, srow, Hrow,
               SWF + OFF_DW1F, SWF + OFF_DW2F, SWF + OFF_DW2TF, SWF + OFF_DW1TF,
               Db1, Db2, Dw3, Db3, gDbf, 0);

    const int lane = tid & 63, w = tid >> 6;
    const int mt = w & 3, nh = w >> 2;
    const int cl = lane & 15, qq = lane >> 4;
    const int arow = mt * 16 + cl;
    const int crow = mt * 16 + qq * 4;

    // ---- u L1 (tanh) -> S1 ----
    {
        short8 a0 = *(const short8*)&zb[arow][(qq << 3)];
        short8 a1 = *(const short8*)&zb[arow][32 + (qq << 3)];
        const ushort_t* W1f = SWF + OFF_UW1F;
        #pragma unroll
        for (int nt = 0; nt < 4; ++nt) {
            int n = nh * 64 + nt * 16 + cl;
            f32x4 acc = {0.f, 0.f, 0.f, 0.f};
            short8 b0 = *(const short8*)&W1f[(n << 5) + (qq << 3)];
            short8 b1 = *(const short8*)&W1f[((128 + n) << 5) + (qq << 3)];
            acc = MFMA(a0, b0, acc); acc = MFMA(a1, b1, acc);
            float bv = ub1[n];
            #pragma unroll
            for (int q = 0; q < 4; ++q)
                S1[crow + q][n] = f2bf(tanhf(acc[q] + bv));
        }
    }
    __syncthreads();
    // ---- u L2 + base write ----
    {
        short8 a[4];
        #pragma unroll
        for (int kt = 0; kt < 4; ++kt)
            a[kt] = *(const short8*)&S1[arow][kt * 32 + (qq << 3)];
        const ushort_t* W2f = SWF + OFF_UW2F;
        const float dtv = 0.1f * sigm(dtl[0]);
        const float et = etg[0];
        #pragma unroll
        for (int ntl = 0; ntl < 2; ++ntl) {
            int n = nh * 32 + ntl * 16 + cl;
            f32x4 acc = {0.f, 0.f, 0.f, 0.f};
            #pragma unroll
            for (int kt = 0; kt < 4; ++kt) {
                short8 bb = *(const short8*)&W2f[((kt * 64 + n) << 5) + (qq << 3)];
                acc = MFMA(a[kt], bb, acc);
            }
            float bv = ub2[n];
            #pragma unroll
            for (int q = 0; q < 4; ++q) {
                int row = crow + q;
                size_t idx = (size_t)(r0 + row) * 64 + n;
                out[idx] = z[idx] + dtv * 0.1f * (et - Hrow[row]) * (acc[q] + bv);
            }
        }
    }
}

// ================= K2: heavy contractions =================
#define LOADHF2(SRC)                                                              \
    do {                                                                          \
        _Pragma("unroll")                                                         \
        for (int q4 = 0; q4 < 4; ++q4) {                                          \
            short8 s8 = *(const short8*)&(SRC)[rr * 136 + q4 * 32 + (qq << 3)];   \
            _Pragma("unroll")                                                     \
            for (int e = 0; e < 4; ++e) {                                         \
                f32x2 t;                                                          \
                t[0] = bf2f((ushort_t)s8[e * 2]);                                 \
                t[1] = bf2f((ushort_t)s8[e * 2 + 1]);                             \
                hf2[q4 * 4 + e] = t;                                              \
            }                                                                     \
        }                                                                         \
    } while (0)

#define HEAVY_PASS(Wbase, BFbase, Gptr, A0, A1, A2, A3)                           \
    do {                                                                          \
        const ushort_t* wpp = (Wbase) + (size_t)kh * 262144 + (cl << 5) + (qq << 3); \
        _Pragma("unroll 1")                                                       \
        for (int kc = 0; kc < 32; ++kc) {                                         \
            const float gj = bf2f((Gptr)[kh * 32 + kc]);                          \
            _Pragma("unroll")                                                     \
            for (int ki = 0; ki < 4; ++ki) {                                      \
                union { unsigned int u[4]; short8 s; } a;                         \
                f32x2 p0 = hf2[ki * 4 + 0] * gj, p1 = hf2[ki * 4 + 1] * gj;       \
                f32x2 p2 = hf2[ki * 4 + 2] * gj, p3 = hf2[ki * 4 + 3] * gj;       \
                a.u[0] = cvtpk(p0[0], p0[1]); a.u[1] = cvtpk(p1[0], p1[1]);       \
                a.u[2] = cvtpk(p2[0], p2[1]); a.u[3] = cvtpk(p3[0], p3[1]);       \
                short8 b0 = *(const short8*)(wpp);                                \
                short8 b1 = *(const short8*)(wpp + 512);                          \
                short8 b2 = *(const short8*)(wpp + 1024);                         \
                short8 b3 = *(const short8*)(wpp + 1536);                         \
                A0 = MFMA(a.s, b0, A0); A1 = MFMA(a.s, b1, A1);                   \
                A2 = MFMA(a.s, b2, A2); A3 = MFMA(a.s, b3, A3);                   \
                wpp += 2048;                                                      \
            }                                                                     \
        }                                                                         \
        {                                                                         \
            short8 ab = *(const short8*)((Gptr) + kh * 32 + (qq << 3));           \
            const ushort_t* bp = (BFbase) + kh * 2048 + (cl << 5) + (qq << 3);    \
            short8 b0 = *(const short8*)(bp);                                     \
            short8 b1 = *(const short8*)(bp + 512);                               \
            short8 b2 = *(const short8*)(bp + 1024);                              \
            short8 b3 = *(const short8*)(bp + 1536);                              \
            A0 = MFMA(ab, b0, A0); A1 = MFMA(ab, b1, A1);                         \
            A2 = MFMA(ab, b2, A2); A3 = MFMA(ab, b3, A3);                         \
        }                                                                         \
    } while (0)

extern "C" __global__ __launch_bounds__(512, 2)
void k2_kernel(const float* __restrict__ z,
               const float* __restrict__ Jb1, const float* __restrict__ Bb1,
               const float* __restrict__ dtl,
               const ushort_t* __restrict__ JW, const ushort_t* __restrict__ BW1,
               const ushort_t* __restrict__ BW2,
               const ushort_t* __restrict__ JbdF, const ushort_t* __restrict__ Bb2F,
               const ushort_t* __restrict__ Bb2TF,
               const ushort_t* __restrict__ SWF,
               const ushort_t* __restrict__ gHbf, const ushort_t* __restrict__ gDbf,
               float* __restrict__ out)
{
    __shared__ __align__(16) char pool[71680];
    ushort_t* zb   = (ushort_t*)(pool);              // [64][72]
    ushort_t* hJ2  = (ushort_t*)(pool + 9216);       // [64][136]
    ushort_t* hB2  = (ushort_t*)(pool + 26624);      // [64][136]
    ushort_t* gHb  = (ushort_t*)(pool + 44032);      // [64][72]
    ushort_t* gDb  = (ushort_t*)(pool + 53248);      // [64][72]
    ushort_t* vb2  = (ushort_t*)(pool + 62464);      // [64][72]
    float*    pcomb = (float*)(pool + 9216);         // [64][68], aliases hJ2

    const int tid = threadIdx.x;
    const int r0 = blockIdx.x * 64;

    // stage
    {
        const float4* zg = (const float4*)(z + (size_t)r0 * 64);
        #pragma unroll
        for (int it = 0; it < 2; ++it) {
            int i = it * 512 + tid;
            float4 v = zg[i];
            int row = i >> 4, c4 = (i & 15) * 4;
            zb[row * 72 + c4 + 0] = f2bf(v.x); zb[row * 72 + c4 + 1] = f2bf(v.y);
            zb[row * 72 + c4 + 2] = f2bf(v.z); zb[row * 72 + c4 + 3] = f2bf(v.w);
        }
        const short8* gh = (const short8*)(gHbf + (size_t)r0 * 64);
        const short8* gd = (const short8*)(gDbf + (size_t)r0 * 64);
        int row = tid >> 3, s = tid & 7;
        *(short8*)&gHb[row * 72 + s * 8] = gh[tid];
        *(short8*)&gDb[row * 72 + s * 8] = gd[tid];
    }
    __syncthreads();

    const int lane = tid & 63, w = tid >> 6;
    const int cl = lane & 15, qq = lane >> 4;
    const int mt = w & 3, nh = w >> 2;     // L1 mapping
    const int rt = mt, kh = nh;            // heavy mapping (same wave->row tile)
    const int arow = mt * 16 + cl;
    const int crowL = mt * 16 + qq * 4;
    const int rr = rt * 16 + cl;
    const int crow = rt * 16 + qq * 4;

    // ---- J/B layer-1 via MFMA ----
    {
        short8 a0 = *(const short8*)&zb[arow * 72 + (qq << 3)];
        short8 a1 = *(const short8*)&zb[arow * 72 + 32 + (qq << 3)];
        const ushort_t* JW1f = SWF + OFF_JW1F;
        const ushort_t* BW1f = SWF + OFF_BW1F;
        #pragma unroll
        for (int nt = 0; nt < 4; ++nt) {
            int n = nh * 64 + nt * 16 + cl;
            f32x4 accJ = {0.f, 0.f, 0.f, 0.f}, accB = {0.f, 0.f, 0.f, 0.f};
            short8 jb0 = *(const short8*)&JW1f[(n << 5) + (qq << 3)];
            short8 jb1 = *(const short8*)&JW1f[((128 + n) << 5) + (qq << 3)];
            accJ = MFMA(a0, jb0, accJ); accJ = MFMA(a1, jb1, accJ);
            short8 bb0 = *(const short8*)&BW1f[(n << 5) + (qq << 3)];
            short8 bb1 = *(const short8*)&BW1f[((128 + n) << 5) + (qq << 3)];
            accB = MFMA(a0, bb0, accB); accB = MFMA(a1, bb1, accB);
            float jbv = Jb1[n], bbv = Bb1[n];
            #pragma unroll
            for (int q = 0; q < 4; ++q) {
                hJ2[(crowL + q) * 136 + n] = f2bf(siluf(accJ[q] + jbv));
                hB2[(crowL + q) * 136 + n] = f2bf(siluf(accB[q] + bbv));
            }
        }
    }
    __syncthreads();

    f32x2 hf2[16];
    f32x4 c0 = {0,0,0,0}, c1 = {0,0,0,0}, c2 = {0,0,0,0}, c3 = {0,0,0,0};
    f32x4 v0 = {0,0,0,0}, v1 = {0,0,0,0}, v2 = {0,0,0,0}, v3 = {0,0,0,0};
    f32x4 d0 = {0,0,0,0}, d1 = {0,0,0,0}, d2 = {0,0,0,0}, d3 = {0,0,0,0};

    // ---- pass 1: cons ----
    LOADHF2(hJ2);
    __syncthreads();            // hJ2 consumed; pcomb (alias) may be written after
    HEAVY_PASS(JW, JbdF, gHb + rr * 72, c0, c1, c2, c3);
    if (kh) {
        #pragma unroll
        for (int q = 0; q < 4; ++q) {
            pcomb[(crow + q) * 68 + 0  + cl] = c0[q];
            pcomb[(crow + q) * 68 + 16 + cl] = c1[q];
            pcomb[(crow + q) * 68 + 32 + cl] = c2[q];
            pcomb[(crow + q) * 68 + 48 + cl] = c3[q];
        }
    }
    __syncthreads();
    if (!kh) {
        #pragma unroll
        for (int q = 0; q < 4; ++q) {
            c0[q] += pcomb[(crow + q) * 68 + 0  + cl];
            c1[q] += pcomb[(crow + q) * 68 + 16 + cl];
            c2[q] += pcomb[(crow + q) * 68 + 32 + cl];
            c3[q] += pcomb[(crow + q) * 68 + 48 + cl];
        }
    }
    __syncthreads();

    // ---- pass 2: v = Bm^T gD ----
    LOADHF2(hB2);
    HEAVY_PASS(BW1, Bb2F, gDb + rr * 72, v0, v1, v2, v3);
    if (kh) {
        #pragma unroll
        for (int q = 0; q < 4; ++q) {
            pcomb[(crow + q) * 68 + 0  + cl] = v0[q];
            pcomb[(crow + q) * 68 + 16 + cl] = v1[q];
            pcomb[(crow + q) * 68 + 32 + cl] = v2[q];
            pcomb[(crow + q) * 68 + 48 + cl] = v3[q];
        }
    }
    __syncthreads();
    if (!kh) {
        #pragma unroll
        for (int q = 0; q < 4; ++q) {
            vb2[(crow + q) * 72 + 0  + cl] = f2bf(v0[q] + pcomb[(crow + q) * 68 + 0  + cl]);
            vb2[(crow + q) * 72 + 16 + cl] = f2bf(v1[q] + pcomb[(crow + q) * 68 + 16 + cl]);
            vb2[(crow + q) * 72 + 32 + cl] = f2bf(v2[q] + pcomb[(crow + q) * 68 + 32 + cl]);
            vb2[(crow + q) * 72 + 48 + cl] = f2bf(v3[q] + pcomb[(crow + q) * 68 + 48 + cl]);
        }
    }
    __syncthreads();

    // ---- pass 3: diss = Bm v (hf2 still holds hB) ----
    HEAVY_PASS(BW2, Bb2TF, vb2 + rr * 72, d0, d1, d2, d3);
    if (kh) {
        #pragma unroll
        for (int q = 0; q < 4; ++q) {
            pcomb[(crow + q) * 68 + 0  + cl] = d0[q];
            pcomb[(crow + q) * 68 + 16 + cl] = d1[q];
            pcomb[(crow + q) * 68 + 32 + cl] = d2[q];
            pcomb[(crow + q) * 68 + 48 + cl] = d3[q];
        }
    }
    __syncthreads();
    if (!kh) {
        const float dtv = 0.1f * sigm(dtl[0]);
        #pragma unroll
        for (int q = 0; q < 4; ++q) {
            d0[q] += pcomb[(crow + q) * 68 + 0  + cl];
            d1[q] += pcomb[(crow + q) * 68 + 16 + cl];
            d2[q] += pcomb[(crow + q) * 68 + 32 + cl];
            d3[q] += pcomb[(crow + q) * 68 + 48 + cl];
        }
        #pragma unroll
        for (int q = 0; q < 4; ++q) {
            size_t base = (size_t)(r0 + crow + q) * 64;
            out[base + 0  + cl] += dtv * (c0[q] - d0[q]);
            out[base + 16 + cl] += dtv * (c1[q] - d1[q]);
            out[base + 32 + cl] += dtv * (c2[q] - d2[q]);
            out[base + 48 + cl] += dtv * (c3[q] - d3[q]);
        }
    }
}

extern "C" void kernel_launch(void* const* d_in, const int* in_sizes, int n_in,
                              void* d_out, int out_size, void* d_ws, size_t ws_size,
                              hipStream_t stream) {
    const float* p[27];
    for (int i = 0; i < 27; ++i) p[i] = (const float*)d_in[i];
    ushort_t* JW    = (ushort_t*)d_ws;
    ushort_t* BW1   = JW + 524288;
    ushort_t* BW2   = BW1 + 524288;
    ushort_t* JbdF  = BW2 + 524288;
    ushort_t* Bb2F  = JbdF + 4096;
    ushort_t* Bb2TF = Bb2F + 4096;
    ushort_t* gHbf  = Bb2TF + 4096;
    ushort_t* gDbf  = gHbf + (size_t)16384 * 64;
    ushort_t* SWF   = gDbf + (size_t)16384 * 64;

    hipLaunchKernelGGL(prep3_kernel, dim3(6657), dim3(256), 0, stream,
                       p[15], p[16], p[19], p[20],
                       p[1], p[3], p[7], p[9],
                       p[21], p[23], p[13], p[17],
                       JW, BW1, BW2, JbdF, Bb2F, Bb2TF, SWF);

    const int batch = in_sizes[0] / DIM;
    hipLaunchKernelGGL(k1_kernel, dim3(batch / 64), dim3(512), 0, stream,
                       p[0],
                       p[2], p[4], p[5], p[6],
                       p[8], p[10], p[11], p[12],
                       p[22], p[24],
                       p[25], p[26],
                       SWF, gHbf, gDbf, (float*)d_out);

    hipLaunchKernelGGL(k2_kernel, dim3(batch / 64), dim3(512), 0, stream,
                       p[0], p[14], p[18], p[25],
                       JW, BW1, BW2, JbdF, Bb2F, Bb2TF, SWF,
                       gHbf, gDbf, (float*)d_out);
}